// Round 1
// baseline (5223.166 us; speedup 1.0000x reference)
//
#include <hip/hip_runtime.h>

#define B_ 4
#define L_ 4096
#define HID_ 1024
#define H_ 16
#define D_ 64
#define DM_ 128
#define CS_ 64
#define NCH_ 64
#define EPS_ 1e-6f

__device__ __forceinline__ float sigf(float x){ return 1.0f/(1.0f + __expf(-x)); }

// XOR quad-swizzle for the W2 LDS tile (stride 68 floats): kills the
// 16-way bank conflict of f4 column-block reads in the g_m @ W2^T phase.
__device__ __forceinline__ int w2idx(int j, int e){
  return j*68 + ((((e>>2) ^ (j&15)) << 2) | (e&3));
}

// ---------------------------------------------------------------------------
// C[M,N] = A[M,K] @ B[N,K]^T   (fp32, both row-major, k contiguous -> NT GEMM)
// 128x128 block tile, 256 threads, 8x8 microtile (split 4+4 at offset 64),
// k-tile 16, LDS stored k-major (transposed) with +4 pad, reg prefetch.
// ---------------------------------------------------------------------------
__global__ __launch_bounds__(256, 2) void gemm_nt_128(
    const float* __restrict__ A, const float* __restrict__ Bw,
    float* __restrict__ C, int M, int N, int Kd)
{
  __shared__ float As[16][132];
  __shared__ float Bs[16][132];
  const int tid = threadIdx.x;
  const int tx = tid & 15, ty = tid >> 4;
  const int m0 = blockIdx.y * 128, n0 = blockIdx.x * 128;
  const int kq = tid & 3, rr = tid >> 2;   // global-load mapping

  const float* pa0 = A  + (size_t)(m0 + rr)      * Kd + kq*4;
  const float* pa1 = A  + (size_t)(m0 + rr + 64) * Kd + kq*4;
  const float* pb0 = Bw + (size_t)(n0 + rr)      * Kd + kq*4;
  const float* pb1 = Bw + (size_t)(n0 + rr + 64) * Kd + kq*4;

  float4 ra0 = *(const float4*)pa0;
  float4 ra1 = *(const float4*)pa1;
  float4 rb0 = *(const float4*)pb0;
  float4 rb1 = *(const float4*)pb1;

  float acc[8][8];
  #pragma unroll
  for (int i=0;i<8;++i)
    #pragma unroll
    for (int j=0;j<8;++j) acc[i][j] = 0.0f;

  const int ktot = Kd >> 4;
  for (int kt = 0; kt < ktot; ++kt){
    const int kc4 = kq*4;
    As[kc4+0][rr] = ra0.x; As[kc4+1][rr] = ra0.y; As[kc4+2][rr] = ra0.z; As[kc4+3][rr] = ra0.w;
    As[kc4+0][rr+64] = ra1.x; As[kc4+1][rr+64] = ra1.y; As[kc4+2][rr+64] = ra1.z; As[kc4+3][rr+64] = ra1.w;
    Bs[kc4+0][rr] = rb0.x; Bs[kc4+1][rr] = rb0.y; Bs[kc4+2][rr] = rb0.z; Bs[kc4+3][rr] = rb0.w;
    Bs[kc4+0][rr+64] = rb1.x; Bs[kc4+1][rr+64] = rb1.y; Bs[kc4+2][rr+64] = rb1.z; Bs[kc4+3][rr+64] = rb1.w;
    __syncthreads();
    if (kt+1 < ktot){
      const int off = (kt+1)*16;
      ra0 = *(const float4*)(pa0 + off);
      ra1 = *(const float4*)(pa1 + off);
      rb0 = *(const float4*)(pb0 + off);
      rb1 = *(const float4*)(pb1 + off);
    }
    #pragma unroll
    for (int kk=0; kk<16; ++kk){
      float av[8], bv[8];
      *(float4*)&av[0] = *(const float4*)&As[kk][ty*4];
      *(float4*)&av[4] = *(const float4*)&As[kk][ty*4+64];
      *(float4*)&bv[0] = *(const float4*)&Bs[kk][tx*4];
      *(float4*)&bv[4] = *(const float4*)&Bs[kk][tx*4+64];
      #pragma unroll
      for (int i=0;i<8;++i)
        #pragma unroll
        for (int j=0;j<8;++j) acc[i][j] += av[i]*bv[j];
    }
    __syncthreads();
  }

  #pragma unroll
  for (int hi=0; hi<2; ++hi){
    #pragma unroll
    for (int r=0;r<4;++r){
      const int row = m0 + hi*64 + ty*4 + r;
      float o0[4], o1[4];
      #pragma unroll
      for (int s=0;s<4;++s){ o0[s] = acc[hi*4+r][s]; o1[s] = acc[hi*4+r][4+s]; }
      *(float4*)&C[(size_t)row*N + n0 + tx*4]      = *(float4*)o0;
      *(float4*)&C[(size_t)row*N + n0 + 64 + tx*4] = *(float4*)o1;
    }
  }
}

// ---------------------------------------------------------------------------
// Gate logits: g[s][b][h][l] = x[b,l,:] . w_s[h,:] + bias_s[h]   (s=0 md,1 sd,2 lr)
// 64 rows per block, 48 gate outputs, k-chunked through LDS.
// ---------------------------------------------------------------------------
__global__ __launch_bounds__(256, 2) void gates_kernel(
  const float* __restrict__ x,
  const float* __restrict__ mdw, const float* __restrict__ mdb,
  const float* __restrict__ sw,  const float* __restrict__ sb,
  const float* __restrict__ lw,  const float* __restrict__ lb,
  float* __restrict__ g)
{
  __shared__ float xs[64][68];
  __shared__ float wg[48][68];
  const int tid = threadIdx.x;
  const int m0 = blockIdx.x * 64;
  const int tx = tid & 15, ty = tid >> 4;
  float acc[4][3];
  #pragma unroll
  for (int r=0;r<4;++r){ acc[r][0]=0.f; acc[r][1]=0.f; acc[r][2]=0.f; }

  for (int k0 = 0; k0 < HID_; k0 += 64){
    {
      const int r = tid >> 2, kq = tid & 3;
      const float* xp = x + (size_t)(m0 + r) * HID_ + k0 + kq*16;
      #pragma unroll
      for (int u=0;u<4;++u){
        float4 v = *(const float4*)(xp + u*4);
        *(float4*)&xs[r][kq*16 + u*4] = v;
      }
    }
    #pragma unroll
    for (int u=0;u<3;++u){
      const int idx = tid + 256*u;
      const int gi = idx >> 4, q = idx & 15;
      const float* wp = (gi < 16) ? (mdw + (size_t)gi*HID_)
                      : (gi < 32) ? (sw  + (size_t)(gi-16)*HID_)
                                  : (lw  + (size_t)(gi-32)*HID_);
      float4 v = *(const float4*)(wp + k0 + q*4);
      *(float4*)&wg[gi][q*4] = v;
    }
    __syncthreads();
    for (int kk=0; kk<64; ++kk){
      float xv[4], wv[3];
      #pragma unroll
      for (int r=0;r<4;++r) xv[r] = xs[ty*4+r][kk];
      #pragma unroll
      for (int gg=0;gg<3;++gg) wv[gg] = wg[tx*3+gg][kk];
      #pragma unroll
      for (int r=0;r<4;++r)
        #pragma unroll
        for (int gg=0;gg<3;++gg) acc[r][gg] += xv[r]*wv[gg];
    }
    __syncthreads();
  }

  #pragma unroll
  for (int gg=0; gg<3; ++gg){
    const int gi = tx*3 + gg;
    const int s = gi >> 4, hh = gi & 15;
    const float bias = (s==0) ? mdb[hh] : (s==1) ? sb[hh] : lb[hh];
    #pragma unroll
    for (int r=0;r<4;++r){
      const int m = m0 + ty*4 + r;
      const int b = m >> 12, l = m & 4095;
      g[(((size_t)s*B_ + b)*H_ + hh)*L_ + l] = acc[r][gg] + bias;
    }
  }
}

// ---------------------------------------------------------------------------
// Sequential chunk scan: one workgroup per (b,h). Fuses causal conv + SiLU +
// RMSNorm staging, all five per-chunk matmuls, decayed reductions (suffix
// products), rank-1 state updates, and the output projection.
// ---------------------------------------------------------------------------
__global__ __launch_bounds__(256, 1) void scan_kernel(
  const float* __restrict__ qraw, const float* __restrict__ kraw, const float* __restrict__ vraw,
  const float* __restrict__ gates,
  const float* __restrict__ cqw, const float* __restrict__ cqb,
  const float* __restrict__ ckw, const float* __restrict__ ckb,
  const float* __restrict__ cvw, const float* __restrict__ cvb,
  const float* __restrict__ qnw, const float* __restrict__ knw,
  const float* __restrict__ W1in, const float* __restrict__ W2in,
  float* __restrict__ out)
{
  const int bh = blockIdx.x;
  const int b = bh >> 4, h = bh & 15;
  const int tid = threadIdx.x;
  const int lane = tid & 63, wave = tid >> 6;
  const int tx = tid & 15, ty = tid >> 4;

  __shared__ float W1sh[D_][DM_];     // 32 KB, state
  __shared__ float W2sh[DM_*68];      // 34.8 KB, state (swizzled)
  __shared__ float kcs[CS_][68];      // staged k (post conv+silu+norm)
  __shared__ float qcs[CS_][68];      // staged q
  __shared__ float gms[CS_][68];      // staged v, then g_m = mems - v
  __shared__ float xbs[CS_][132];     // X1, then gZ1_pre, then hq
  __shared__ float cm_[CS_], c1_[CS_];
  __shared__ float kmomS[D_], w2momS[D_];
  __shared__ float xmomS[DM_], w1momS[DM_];
  __shared__ float Pmd_s, Psd_s;

  // ---- init state ----
  {
    const float* w1p = W1in + (size_t)h * D_ * DM_;
    for (int t = tid; t < D_*DM_; t += 256){
      W1sh[t >> 7][t & 127] = w1p[t];
    }
    const float* w2p = W2in + (size_t)h * DM_ * D_;
    for (int t = tid; t < DM_*D_; t += 256){
      W2sh[w2idx(t >> 6, t & 63)] = w2p[t];
    }
    if (tid < D_) { kmomS[tid] = 0.0f; w2momS[tid] = 0.0f; }
    if (tid < DM_){ xmomS[tid] = 0.0f; w1momS[tid] = 0.0f; }
  }
  // per-lane conv weights (channel c = h*64 + lane), invariant over chunks
  const int c = h*64 + lane;
  float wkc[4], wqc[4], wvc[4];
  #pragma unroll
  for (int kk=0;kk<4;++kk){ wkc[kk]=ckw[c*4+kk]; wqc[kk]=cqw[c*4+kk]; wvc[kk]=cvw[c*4+kk]; }
  const float bkc = ckb[c], bqc = cqb[c], bvc = cvb[c];
  const float knorm = knw[lane], qnorm = qnw[lane];
  __syncthreads();

  for (int n = 0; n < NCH_; ++n){
    const int l0 = n * CS_;

    // ---- P0: gates + suffix products (wave 0) ----
    if (wave == 0){
      const size_t gb = ((size_t)b * H_ + h) * L_ + l0 + lane;
      const size_t GS = (size_t)B_*H_*L_;
      float md = 1.0f - sigf(gates[gb]);
      float sd = sigf(gates[GS + gb]);
      float lr = sigf(gates[2*GS + gb]);
      float vm = md, vs = sd;
      #pragma unroll
      for (int off = 1; off < 64; off <<= 1){
        float om = __shfl_down(vm, off);
        float os = __shfl_down(vs, off);
        if (lane + off < 64){ vm *= om; vs *= os; }
      }
      float mex = __shfl_down(vm, 1);
      float sex = __shfl_down(vs, 1);
      if (lane == 63){ mex = 1.0f; sex = 1.0f; }
      cm_[lane] = mex;            // suffix-exclusive prod of md
      c1_[lane] = -lr * sex;      // -lr * suffix-exclusive prod of sd
      if (lane == 0){ Pmd_s = vm; Psd_s = vs; }
    }

    // ---- P1: stage conv+silu(+rmsnorm) for k,q,v (wave w: rows 16w..16w+15) ----
    for (int rr2 = 0; rr2 < 16; ++rr2){
      const int i = wave*16 + rr2;
      const int l = l0 + i;
      const long rb = (long)((size_t)b * L_ + l) * HID_ + c;
      float ak = bkc, aq = bqc, av = bvc;
      #pragma unroll
      for (int kk = 0; kk < 4; ++kk){
        const int ls = l - 3 + kk;
        if (ls >= 0){
          const long off = rb + (long)(kk-3) * HID_;
          ak += wkc[kk] * kraw[off];
          aq += wqc[kk] * qraw[off];
          av += wvc[kk] * vraw[off];
        }
      }
      const float yk = ak * sigf(ak);
      const float yq = aq * sigf(aq);
      const float yv = av * sigf(av);
      float ssk = yk*yk, ssq = yq*yq;
      #pragma unroll
      for (int o2 = 32; o2 >= 1; o2 >>= 1){ ssk += __shfl_xor(ssk, o2); ssq += __shfl_xor(ssq, o2); }
      kcs[i][lane] = knorm * yk * rsqrtf(ssk * (1.0f/64.0f) + EPS_);
      qcs[i][lane] = qnorm * yq * rsqrtf(ssq * (1.0f/64.0f) + EPS_);
      gms[i][lane] = yv;
    }
    __syncthreads();

    const float Pmd = Pmd_s, Psd = Psd_s;

    // ---- P2: Z1 = kc @ W1 ; X1 = silu(Z1) -> xbs ; keep Z1 in regs ----
    float z[4][8];
    #pragma unroll
    for (int r=0;r<4;++r)
      #pragma unroll
      for (int s=0;s<8;++s) z[r][s] = 0.0f;
    for (int d0=0; d0<D_; d0+=4){
      float ka[4][4];
      #pragma unroll
      for (int r=0;r<4;++r) *(float4*)ka[r] = *(const float4*)&kcs[ty*4+r][d0];
      #pragma unroll
      for (int dd=0; dd<4; ++dd){
        float wv[8];
        *(float4*)&wv[0] = *(const float4*)&W1sh[d0+dd][tx*4];
        *(float4*)&wv[4] = *(const float4*)&W1sh[d0+dd][tx*4+64];
        #pragma unroll
        for (int r=0;r<4;++r){
          const float a = ka[r][dd];
          #pragma unroll
          for (int s=0;s<8;++s) z[r][s] += a * wv[s];
        }
      }
    }
    #pragma unroll
    for (int r=0;r<4;++r){
      const int i = ty*4+r;
      float xo[8];
      #pragma unroll
      for (int s=0;s<8;++s) xo[s] = z[r][s] * sigf(z[r][s]);
      *(float4*)&xbs[i][tx*4]    = *(float4*)&xo[0];
      *(float4*)&xbs[i][tx*4+64] = *(float4*)&xo[4];
    }
    __syncthreads();

    // ---- P3: kmom (thr 0..63), xmom (thr 64..191) ----
    if (tid < 64){
      const int d = tid;
      float a = Pmd * kmomS[d];
      for (int i=0;i<64;++i) a += cm_[i]*kcs[i][d];
      kmomS[d] = a;
    } else if (tid < 192){
      const int j = tid - 64;
      float a = Pmd * xmomS[j];
      for (int i=0;i<64;++i) a += cm_[i]*xbs[i][j];
      xmomS[j] = a;
    }

    // ---- P4: g_m = X1 @ W2 - vc  (in place in gms) ----
    {
      float mm[4][4];
      #pragma unroll
      for (int r=0;r<4;++r){ mm[r][0]=0.f; mm[r][1]=0.f; mm[r][2]=0.f; mm[r][3]=0.f; }
      for (int j0=0; j0<DM_; j0+=4){
        float xv[4][4];
        #pragma unroll
        for (int r=0;r<4;++r) *(float4*)xv[r] = *(const float4*)&xbs[ty*4+r][j0];
        #pragma unroll
        for (int jj=0;jj<4;++jj){
          float wv[4];
          *(float4*)wv = *(const float4*)&W2sh[w2idx(j0+jj, tx*4)];
          #pragma unroll
          for (int r=0;r<4;++r){
            const float a = xv[r][jj];
            #pragma unroll
            for (int s=0;s<4;++s) mm[r][s] += a*wv[s];
          }
        }
      }
      #pragma unroll
      for (int r=0;r<4;++r){
        const int i = ty*4+r;
        float4 old = *(float4*)&gms[i][tx*4];
        float go[4] = { mm[r][0]-old.x, mm[r][1]-old.y, mm[r][2]-old.z, mm[r][3]-old.w };
        *(float4*)&gms[i][tx*4] = *(float4*)go;
      }
    }
    __syncthreads();

    // ---- P5: gZ1_pre = (g_m @ W2^T) * silu_bwd(Z1) -> xbs (overwrites X1) ----
    {
      float gz[4][8];
      #pragma unroll
      for (int r=0;r<4;++r)
        #pragma unroll
        for (int s=0;s<8;++s) gz[r][s] = 0.0f;
      for (int e0=0; e0<D_; e0+=4){
        float gv[4][4];
        #pragma unroll
        for (int r=0;r<4;++r) *(float4*)gv[r] = *(const float4*)&gms[ty*4+r][e0];
        float wv[8][4];
        #pragma unroll
        for (int s=0;s<4;++s) *(float4*)wv[s]   = *(const float4*)&W2sh[w2idx(tx*4+s, e0)];
        #pragma unroll
        for (int s=0;s<4;++s) *(float4*)wv[4+s] = *(const float4*)&W2sh[w2idx(64+tx*4+s, e0)];
        #pragma unroll
        for (int ee=0; ee<4; ++ee){
          #pragma unroll
          for (int r=0;r<4;++r){
            const float a = gv[r][ee];
            #pragma unroll
            for (int s=0;s<8;++s) gz[r][s] += a * wv[s][ee];
          }
        }
      }
      #pragma unroll
      for (int r=0;r<4;++r){
        const int i = ty*4+r;
        float xo[8];
        #pragma unroll
        for (int s=0;s<8;++s){
          const float zz = z[r][s];
          const float sg = sigf(zz);
          xo[s] = gz[r][s] * (sg * (1.0f + zz * (1.0f - sg)));
        }
        *(float4*)&xbs[i][tx*4]    = *(float4*)&xo[0];
        *(float4*)&xbs[i][tx*4+64] = *(float4*)&xo[4];
      }
    }
    __syncthreads();

    // ---- P6: w1mom (thr 0..127), w2mom (thr 128..191) ----
    if (tid < 128){
      const int j = tid;
      float a = Psd * w1momS[j];
      for (int i=0;i<64;++i) a += c1_[i]*xbs[i][j];
      w1momS[j] = a;
    } else if (tid < 192){
      const int e = tid - 128;
      float a = Psd * w2momS[e];
      for (int i=0;i<64;++i) a += c1_[i]*gms[i][e];
      w2momS[e] = a;
    }
    __syncthreads();

    // ---- P7: rank-1 state updates ----
    #pragma unroll
    for (int u=0;u<8;++u){
      const int f = tid + 256*u;
      const int d = f >> 5, q = f & 31;
      float4 wv = *(float4*)&W1sh[d][q*4];
      const float km = kmomS[d];
      float4 m1 = *(const float4*)&w1momS[q*4];
      wv.x = Pmd*wv.x + km*m1.x; wv.y = Pmd*wv.y + km*m1.y;
      wv.z = Pmd*wv.z + km*m1.z; wv.w = Pmd*wv.w + km*m1.w;
      *(float4*)&W1sh[d][q*4] = wv;
    }
    #pragma unroll
    for (int u=0;u<8;++u){
      const int f = tid + 256*u;
      const int j = f >> 4, qe = f & 15;
      const int idx = w2idx(j, qe*4);
      float4 wv = *(float4*)&W2sh[idx];
      const float xm = xmomS[j];
      float4 m2 = *(const float4*)&w2momS[qe*4];
      wv.x = Pmd*wv.x + xm*m2.x; wv.y = Pmd*wv.y + xm*m2.y;
      wv.z = Pmd*wv.z + xm*m2.z; wv.w = Pmd*wv.w + xm*m2.w;
      *(float4*)&W2sh[idx] = wv;
    }
    __syncthreads();

    // ---- P8: hq = silu(qc @ W1new) -> xbs ----
    {
      float hqv[4][8];
      #pragma unroll
      for (int r=0;r<4;++r)
        #pragma unroll
        for (int s=0;s<8;++s) hqv[r][s] = 0.0f;
      for (int d0=0; d0<D_; d0+=4){
        float qa[4][4];
        #pragma unroll
        for (int r=0;r<4;++r) *(float4*)qa[r] = *(const float4*)&qcs[ty*4+r][d0];
        #pragma unroll
        for (int dd=0; dd<4; ++dd){
          float wv[8];
          *(float4*)&wv[0] = *(const float4*)&W1sh[d0+dd][tx*4];
          *(float4*)&wv[4] = *(const float4*)&W1sh[d0+dd][tx*4+64];
          #pragma unroll
          for (int r=0;r<4;++r){
            const float a = qa[r][dd];
            #pragma unroll
            for (int s=0;s<8;++s) hqv[r][s] += a * wv[s];
          }
        }
      }
      #pragma unroll
      for (int r=0;r<4;++r){
        const int i = ty*4+r;
        float xo[8];
        #pragma unroll
        for (int s=0;s<8;++s){ const float v = hqv[r][s]; xo[s] = v * sigf(v); }
        *(float4*)&xbs[i][tx*4]    = *(float4*)&xo[0];
        *(float4*)&xbs[i][tx*4+64] = *(float4*)&xo[4];
      }
    }
    __syncthreads();

    // ---- P9: y = hq @ W2new -> out (out layout (B,H,D,L)) ----
    {
      float yy[4][4];
      #pragma unroll
      for (int r=0;r<4;++r){ yy[r][0]=0.f; yy[r][1]=0.f; yy[r][2]=0.f; yy[r][3]=0.f; }
      for (int j0=0; j0<DM_; j0+=4){
        float xv[4][4];
        #pragma unroll
        for (int r=0;r<4;++r) *(float4*)xv[r] = *(const float4*)&xbs[ty*4+r][j0];
        #pragma unroll
        for (int jj=0;jj<4;++jj){
          float wv[4];
          *(float4*)wv = *(const float4*)&W2sh[w2idx(j0+jj, tx*4)];
          #pragma unroll
          for (int r=0;r<4;++r){
            const float a = xv[r][jj];
            #pragma unroll
            for (int s=0;s<4;++s) yy[r][s] += a*wv[s];
          }
        }
      }
      const size_t ob = (size_t)bh * D_ * L_;
      #pragma unroll
      for (int s=0;s<4;++s){
        float ov[4] = { yy[0][s], yy[1][s], yy[2][s], yy[3][s] };
        *(float4*)&out[ob + (size_t)(tx*4+s)*L_ + l0 + ty*4] = *(float4*)ov;
      }
    }
    // no barrier needed here: next chunk's first barrier (end of P1) protects
  }
}

extern "C" void kernel_launch(void* const* d_in, const int* in_sizes, int n_in,
                              void* d_out, int out_size, void* d_ws, size_t ws_size,
                              hipStream_t stream)
{
  const float* x   = (const float*)d_in[0];
  const float* Wq  = (const float*)d_in[1];
  const float* Wk  = (const float*)d_in[2];
  const float* Wv  = (const float*)d_in[3];
  const float* cqw = (const float*)d_in[4];
  const float* cqb = (const float*)d_in[5];
  const float* ckw = (const float*)d_in[6];
  const float* ckb = (const float*)d_in[7];
  const float* cvw = (const float*)d_in[8];
  const float* cvb = (const float*)d_in[9];
  const float* qnw = (const float*)d_in[10];
  const float* knw = (const float*)d_in[11];
  const float* mdw = (const float*)d_in[12];
  const float* mdb = (const float*)d_in[13];
  const float* sw  = (const float*)d_in[14];
  const float* sb  = (const float*)d_in[15];
  const float* lw  = (const float*)d_in[16];
  const float* lb  = (const float*)d_in[17];
  const float* W1  = (const float*)d_in[18];
  const float* W2  = (const float*)d_in[19];
  float* out = (float*)d_out;
  float* ws  = (float*)d_ws;

  const size_t SZ = (size_t)B_ * L_ * HID_;
  float* qraw = ws;
  float* kraw = ws + SZ;
  float* vraw = ws + 2*SZ;
  float* gts  = ws + 3*SZ;   // 3*B*H*L floats

  dim3 gg(HID_/128, (B_*L_)/128);
  gemm_nt_128<<<gg, 256, 0, stream>>>(x, Wq, qraw, B_*L_, HID_, HID_);
  gemm_nt_128<<<gg, 256, 0, stream>>>(x, Wk, kraw, B_*L_, HID_, HID_);
  gemm_nt_128<<<gg, 256, 0, stream>>>(x, Wv, vraw, B_*L_, HID_, HID_);
  gates_kernel<<<(B_*L_)/64, 256, 0, stream>>>(x, mdw, mdb, sw, sb, lw, lb, gts);
  scan_kernel<<<B_*H_, 256, 0, stream>>>(qraw, kraw, vraw, gts,
                                         cqw, cqb, ckw, ckb, cvw, cvb,
                                         qnw, knw, W1, W2, out);
}

// Round 2
// 2904.882 us; speedup vs baseline: 1.7981x; 1.7981x over previous
//
#include <hip/hip_runtime.h>

#define B_ 4
#define L_ 4096
#define HID_ 1024
#define H_ 16
#define D_ 64
#define DM_ 128
#define CS_ 64
#define NCH_ 64
#define EPS_ 1e-6f

typedef __attribute__((ext_vector_type(8))) short bfrag_t;   // 8 bf16 = 4 VGPRs
typedef __attribute__((ext_vector_type(4))) float facc_t;    // MFMA C/D

#define MFMA16(a,b,c) __builtin_amdgcn_mfma_f32_16x16x32_bf16(a,b,c,0,0,0)

__device__ __forceinline__ float sigf(float x){ return 1.0f/(1.0f + __expf(-x)); }

__device__ __forceinline__ unsigned f2bfu(float x){   // fp32 -> bf16 RNE
  unsigned u = __float_as_uint(x);
  return (u + 0x7fffu + ((u>>16)&1u)) >> 16;
}
__device__ __forceinline__ float bf2f(unsigned short s){
  return __uint_as_float(((unsigned)s)<<16);
}

// Pack-write a 16x16 MFMA C-tile (4 regs) as bf16 into LDS, pairing adjacent
// lanes so every LDS write is a full b32 (no same-dword b16 collisions).
__device__ __forceinline__ void tile_store_bf16(unsigned* d32, int strideDW,
    int row0, int col, float v0, float v1, float v2, float v3, int lane){
  unsigned b0=f2bfu(v0), b1=f2bfu(v1), b2=f2bfu(v2), b3=f2bfu(v3);
  unsigned p01 = b0 | (b1<<16), p23 = b2 | (b3<<16);
  unsigned q01 = (unsigned)__shfl_xor((int)p01, 1);
  unsigned q23 = (unsigned)__shfl_xor((int)p23, 1);
  const int cd = col>>1;
  if (!(lane & 1)){
    d32[(row0+0)*strideDW + cd] = (p01 & 0xffffu) | (q01 << 16);
    d32[(row0+1)*strideDW + cd] = (p01 >> 16)     | (q01 & 0xffff0000u);
  } else {
    d32[(row0+2)*strideDW + cd] = (q23 & 0xffffu) | (p23 << 16);
    d32[(row0+3)*strideDW + cd] = (q23 >> 16)     | (p23 & 0xffff0000u);
  }
}

// ---------------------------------------------------------------------------
// cast fp32 -> bf16 for x (16384x1024) and Wq/Wk/Wv (1024x1024 each)
// ---------------------------------------------------------------------------
__global__ __launch_bounds__(256) void cast_kernel(
    const float* __restrict__ x,  const float* __restrict__ wq,
    const float* __restrict__ wk, const float* __restrict__ wv,
    unsigned short* __restrict__ xb,  unsigned short* __restrict__ wqb,
    unsigned short* __restrict__ wkb, unsigned short* __restrict__ wvb)
{
  const int bid = blockIdx.x;
  const float* s; unsigned short* d; int base;
  if (bid < 16384){ s = x; d = xb; base = bid*1024; }
  else {
    int r = bid - 16384; const int a = r >> 10; r &= 1023; base = r*1024;
    s = (a==0)?wq:(a==1)?wk:wv;
    d = (a==0)?wqb:(a==1)?wkb:wvb;
  }
  const int i = base + threadIdx.x*4;
  float4 v = *(const float4*)(s + i);
  unsigned lo = f2bfu(v.x) | (f2bfu(v.y)<<16);
  unsigned hi = f2bfu(v.z) | (f2bfu(v.w)<<16);
  uint2 o; o.x = lo; o.y = hi;
  *(uint2*)(d + i) = o;
}

// ---------------------------------------------------------------------------
// C[M,N](bf16) = A[M,K](bf16) @ B[N,K]^T(bf16) ; 128x128 tile, BK=32,
// 16x16x32 bf16 MFMA, 256 threads (4 waves, each a 64x64 quadrant).
// ---------------------------------------------------------------------------
__global__ __launch_bounds__(256, 2) void gemm_bf16_nt(
    const unsigned short* __restrict__ A, const unsigned short* __restrict__ Bw,
    unsigned short* __restrict__ C, int M, int N, int K)
{
  __shared__ __align__(16) unsigned short As[128*32];
  __shared__ __align__(16) unsigned short Bs[128*32];
  const int tid = threadIdx.x;
  const int lane = tid & 63, wave = tid >> 6;
  const int lq = lane & 15, quad = lane >> 4;
  const int m0 = blockIdx.y*128, n0 = blockIdx.x*128;
  const int row = tid >> 2, ks = (tid & 3)*8;
  const int mo = (wave & 1)*64, no = (wave >> 1)*64;

  const unsigned short* pa0 = A  + (size_t)(m0 + row)*K + ks;
  const unsigned short* pa1 = pa0 + (size_t)64*K;
  const unsigned short* pb0 = Bw + (size_t)(n0 + row)*K + ks;
  const unsigned short* pb1 = pb0 + (size_t)64*K;

  uint4 ra0 = *(const uint4*)pa0;
  uint4 ra1 = *(const uint4*)pa1;
  uint4 rb0 = *(const uint4*)pb0;
  uint4 rb1 = *(const uint4*)pb1;

  facc_t acc[4][4];
  #pragma unroll
  for (int i=0;i<4;++i)
    #pragma unroll
    for (int j=0;j<4;++j) acc[i][j] = (facc_t){0.f,0.f,0.f,0.f};

  const int kiters = K >> 5;
  for (int kt = 0; kt < kiters; ++kt){
    *(uint4*)&As[row*32 + ks]      = ra0;
    *(uint4*)&As[(row+64)*32 + ks] = ra1;
    *(uint4*)&Bs[row*32 + ks]      = rb0;
    *(uint4*)&Bs[(row+64)*32 + ks] = rb1;
    __syncthreads();
    if (kt+1 < kiters){
      const int off = (kt+1)*32;
      ra0 = *(const uint4*)(pa0 + off);
      ra1 = *(const uint4*)(pa1 + off);
      rb0 = *(const uint4*)(pb0 + off);
      rb1 = *(const uint4*)(pb1 + off);
    }
    bfrag_t af[4], bf[4];
    #pragma unroll
    for (int mt=0;mt<4;++mt) af[mt] = *(const bfrag_t*)&As[(mo+mt*16+lq)*32 + quad*8];
    #pragma unroll
    for (int nt=0;nt<4;++nt) bf[nt] = *(const bfrag_t*)&Bs[(no+nt*16+lq)*32 + quad*8];
    #pragma unroll
    for (int mt=0;mt<4;++mt)
      #pragma unroll
      for (int nt=0;nt<4;++nt)
        acc[mt][nt] = MFMA16(af[mt], bf[nt], acc[mt][nt]);
    __syncthreads();
  }

  #pragma unroll
  for (int mt=0;mt<4;++mt)
    #pragma unroll
    for (int nt=0;nt<4;++nt)
      #pragma unroll
      for (int r=0;r<4;++r){
        const int rr = m0 + mo + mt*16 + quad*4 + r;
        const int cc = n0 + no + nt*16 + lq;
        C[(size_t)rr*N + cc] = (unsigned short)f2bfu(acc[mt][nt][r]);
      }
}

// ---------------------------------------------------------------------------
// Gate logits (fp32): g[s][b][h][l] = x . w_s[h] + b_s[h]
// ---------------------------------------------------------------------------
__global__ __launch_bounds__(256, 2) void gates_kernel(
  const float* __restrict__ x,
  const float* __restrict__ mdw, const float* __restrict__ mdb,
  const float* __restrict__ sw,  const float* __restrict__ sb,
  const float* __restrict__ lw,  const float* __restrict__ lb,
  float* __restrict__ g)
{
  __shared__ float xs[64][68];
  __shared__ float wg[48][68];
  const int tid = threadIdx.x;
  const int m0 = blockIdx.x * 64;
  const int tx = tid & 15, ty = tid >> 4;
  float acc[4][3];
  #pragma unroll
  for (int r=0;r<4;++r){ acc[r][0]=0.f; acc[r][1]=0.f; acc[r][2]=0.f; }

  for (int k0 = 0; k0 < HID_; k0 += 64){
    {
      const int r = tid >> 2, kq = tid & 3;
      const float* xp = x + (size_t)(m0 + r) * HID_ + k0 + kq*16;
      #pragma unroll
      for (int u=0;u<4;++u){
        float4 v = *(const float4*)(xp + u*4);
        *(float4*)&xs[r][kq*16 + u*4] = v;
      }
    }
    #pragma unroll
    for (int u=0;u<3;++u){
      const int idx = tid + 256*u;
      const int gi = idx >> 4, q = idx & 15;
      const float* wp = (gi < 16) ? (mdw + (size_t)gi*HID_)
                      : (gi < 32) ? (sw  + (size_t)(gi-16)*HID_)
                                  : (lw  + (size_t)(gi-32)*HID_);
      float4 v = *(const float4*)(wp + k0 + q*4);
      *(float4*)&wg[gi][q*4] = v;
    }
    __syncthreads();
    for (int kk=0; kk<64; ++kk){
      float xv[4], wv[3];
      #pragma unroll
      for (int r=0;r<4;++r) xv[r] = xs[ty*4+r][kk];
      #pragma unroll
      for (int gg=0;gg<3;++gg) wv[gg] = wg[tx*3+gg][kk];
      #pragma unroll
      for (int r=0;r<4;++r)
        #pragma unroll
        for (int gg=0;gg<3;++gg) acc[r][gg] += xv[r]*wv[gg];
    }
    __syncthreads();
  }

  #pragma unroll
  for (int gg=0; gg<3; ++gg){
    const int gi = tx*3 + gg;
    const int s = gi >> 4, hh = gi & 15;
    const float bias = (s==0) ? mdb[hh] : (s==1) ? sb[hh] : lb[hh];
    #pragma unroll
    for (int r=0;r<4;++r){
      const int m = m0 + ty*4 + r;
      const int b = m >> 12, l = m & 4095;
      g[(((size_t)s*B_ + b)*H_ + hh)*L_ + l] = acc[r][gg] + bias;
    }
  }
}

// ---------------------------------------------------------------------------
// MFMA chunk scan: one workgroup per (b,h). bf16 operands in LDS (strides
// 80/144 bf16 == 8 dw mod 32 -> conflict-free b128 frag reads), fp32 gates /
// momenta / accumulation. State W1/W2 kept as bf16 (decay Pmd~2^-64 kills
// cross-chunk error accumulation).
// ---------------------------------------------------------------------------
#define SK 80    // stride (bf16) of 64-wide arrays
#define SX 144   // stride (bf16) of 128-wide arrays

__global__ __launch_bounds__(256, 1) void scan_kernel(
  const unsigned short* __restrict__ qraw, const unsigned short* __restrict__ kraw,
  const unsigned short* __restrict__ vraw,
  const float* __restrict__ gates,
  const float* __restrict__ cqw, const float* __restrict__ cqb,
  const float* __restrict__ ckw, const float* __restrict__ ckb,
  const float* __restrict__ cvw, const float* __restrict__ cvb,
  const float* __restrict__ qnw, const float* __restrict__ knw,
  const float* __restrict__ W1in, const float* __restrict__ W2in,
  float* __restrict__ out)
{
  const int bh = blockIdx.x;
  const int b = bh >> 4, h = bh & 15;
  const int tid = threadIdx.x;
  const int lane = tid & 63, wave = tid >> 6;
  const int lq = lane & 15, quad = lane >> 4;
  const int m0 = wave * 16;            // this wave's row slab in all matmuls

  __shared__ __align__(16) unsigned short smem[54272];
  unsigned short* kcs = smem;            // [64][SK]
  unsigned short* qcs = smem + 5120;     // [64][SK]
  unsigned short* gms = smem + 10240;    // [64][SK]  v, then g_m
  unsigned short* xbs = smem + 15360;    // [64][SX]  X1 -> gZ1 -> hq
  unsigned short* W1T = smem + 24576;    // [128 j][SK] (k=d contiguous)
  unsigned short* W2n = smem + 34816;    // [128 j][SK] (k=e contiguous)
  unsigned short* W2T = smem + 45056;    // [64 e][SX]  (k=j contiguous)
  unsigned* kcs32 = (unsigned*)kcs;
  unsigned* qcs32 = (unsigned*)qcs;
  unsigned* gms32 = (unsigned*)gms;
  unsigned* xbs32 = (unsigned*)xbs;
  unsigned* W2T32 = (unsigned*)W2T;

  __shared__ float cm_[CS_], c1_[CS_];
  __shared__ float kmomS[D_], w2momS[D_];
  __shared__ float xmomS[DM_], w1momS[DM_];
  __shared__ float PmdS, PsdS;

  // ---- init state ----
  {
    const int j = tid >> 1, half = (tid & 1)*32;
    const float* w1p = W1in + (size_t)h * D_ * DM_;   // [d][j]
    #pragma unroll 8
    for (int i=0;i<32;++i)
      W1T[j*SK + half + i] = (unsigned short)f2bfu(w1p[(size_t)(half+i)*DM_ + j]);
    const float* w2p = W2in + (size_t)h * DM_ * D_;   // [j][e]
    #pragma unroll 8
    for (int i=0;i<32;++i){
      unsigned short v = (unsigned short)f2bfu(w2p[(size_t)j*D_ + half + i]);
      W2n[j*SK + half + i] = v;
      W2T[(half+i)*SX + j] = v;
    }
    if (tid < D_) { kmomS[tid] = 0.f; w2momS[tid] = 0.f; }
    if (tid < DM_){ xmomS[tid] = 0.f; w1momS[tid] = 0.f; }
  }
  const int c = h*64 + lane;
  float wkc[4], wqc[4], wvc[4];
  #pragma unroll
  for (int kk=0;kk<4;++kk){ wkc[kk]=ckw[c*4+kk]; wqc[kk]=cqw[c*4+kk]; wvc[kk]=cvw[c*4+kk]; }
  const float bkc = ckb[c], bqc = cqb[c], bvc = cvb[c];
  const float knf = knw[lane], qnf = qnw[lane];
  const long xbase = (long)b * L_ * HID_ + c;
  __syncthreads();

  for (int n = 0; n < NCH_; ++n){
    const int l0 = n * CS_;

    // ---- P0: gates + suffix products (wave 0 only) ----
    if (wave == 0){
      const size_t gb = ((size_t)b * H_ + h) * L_ + l0 + lane;
      const size_t GS = (size_t)B_*H_*L_;
      float md = 1.0f - sigf(gates[gb]);
      float sd = sigf(gates[GS + gb]);
      float lr = sigf(gates[2*GS + gb]);
      float vm = md, vs = sd;
      #pragma unroll
      for (int off = 1; off < 64; off <<= 1){
        float om = __shfl_down(vm, off);
        float os = __shfl_down(vs, off);
        if (lane + off < 64){ vm *= om; vs *= os; }
      }
      float mex = __shfl_down(vm, 1);
      float sex = __shfl_down(vs, 1);
      if (lane == 63){ mex = 1.0f; sex = 1.0f; }
      cm_[lane] = mex;
      c1_[lane] = -lr * sex;
      if (lane == 0){ PmdS = vm; PsdS = vs; }
    }

    // ---- P1: conv+silu(+rmsnorm) staging -> kcs,qcs,gms(v)  (bf16) ----
    {
      const int r0 = l0 + m0;
      float hk0,hk1,hk2, hq0,hq1,hq2, hv0,hv1,hv2;
      {
        int l = r0-3; long o = xbase + (long)l*HID_;
        hk0 = (l>=0)? bf2f(kraw[o]) : 0.f; hq0 = (l>=0)? bf2f(qraw[o]) : 0.f; hv0 = (l>=0)? bf2f(vraw[o]) : 0.f;
        l = r0-2; o = xbase + (long)l*HID_;
        hk1 = (l>=0)? bf2f(kraw[o]) : 0.f; hq1 = (l>=0)? bf2f(qraw[o]) : 0.f; hv1 = (l>=0)? bf2f(vraw[o]) : 0.f;
        l = r0-1; o = xbase + (long)l*HID_;
        hk2 = (l>=0)? bf2f(kraw[o]) : 0.f; hq2 = (l>=0)? bf2f(qraw[o]) : 0.f; hv2 = (l>=0)? bf2f(vraw[o]) : 0.f;
      }
      for (int i=0;i<16;++i){
        const long o = xbase + (long)(r0+i)*HID_;
        const float ckr = bf2f(kraw[o]), cqr = bf2f(qraw[o]), cvr = bf2f(vraw[o]);
        float ak = bkc + wkc[0]*hk0 + wkc[1]*hk1 + wkc[2]*hk2 + wkc[3]*ckr;
        float aq = bqc + wqc[0]*hq0 + wqc[1]*hq1 + wqc[2]*hq2 + wqc[3]*cqr;
        float av = bvc + wvc[0]*hv0 + wvc[1]*hv1 + wvc[2]*hv2 + wvc[3]*cvr;
        hk0=hk1; hk1=hk2; hk2=ckr;
        hq0=hq1; hq1=hq2; hq2=cqr;
        hv0=hv1; hv1=hv2; hv2=cvr;
        const float yk = ak*sigf(ak), yq = aq*sigf(aq), yv = av*sigf(av);
        float ssk = yk*yk, ssq = yq*yq;
        #pragma unroll
        for (int o2=32;o2>=1;o2>>=1){ ssk += __shfl_xor(ssk,o2); ssq += __shfl_xor(ssq,o2); }
        const float vk = knf * yk * rsqrtf(ssk*(1.0f/64.0f) + EPS_);
        const float vq = qnf * yq * rsqrtf(ssq*(1.0f/64.0f) + EPS_);
        unsigned bk = f2bfu(vk), bq = f2bfu(vq), bv = f2bfu(yv);
        unsigned pk = (unsigned)__shfl_xor((int)bk,1);
        unsigned pq = (unsigned)__shfl_xor((int)bq,1);
        unsigned pv = (unsigned)__shfl_xor((int)bv,1);
        if (!(lane & 1)){
          const int dw = (m0+i)*(SK/2) + (lane>>1);
          kcs32[dw] = bk | (pk<<16);
          qcs32[dw] = bq | (pq<<16);
          gms32[dw] = bv | (pv<<16);
        }
      }
    }
    __syncthreads();
    const float Pmd = PmdS, Psd = PsdS;

    // ---- P2: Z1 = kc @ W1 ; X1 = silu(Z1) -> xbs ; keep Z1 in regs ----
    facc_t zk[8];
    {
      const bfrag_t a0 = *(const bfrag_t*)&kcs[(m0+lq)*SK + quad*8];
      const bfrag_t a1 = *(const bfrag_t*)&kcs[(m0+lq)*SK + 32 + quad*8];
      #pragma unroll
      for (int nt=0;nt<8;++nt){
        facc_t z = {0.f,0.f,0.f,0.f};
        const bfrag_t b0 = *(const bfrag_t*)&W1T[(nt*16+lq)*SK + quad*8];
        const bfrag_t b1 = *(const bfrag_t*)&W1T[(nt*16+lq)*SK + 32 + quad*8];
        z = MFMA16(a0, b0, z);
        z = MFMA16(a1, b1, z);
        zk[nt] = z;
        tile_store_bf16(xbs32, SX/2, m0+quad*4, nt*16+lq,
                        z[0]*sigf(z[0]), z[1]*sigf(z[1]), z[2]*sigf(z[2]), z[3]*sigf(z[3]), lane);
      }
    }
    __syncthreads();

    // ---- P3: kmom / xmom (decayed column reductions) ----
    if (tid < 64){
      float a = Pmd * kmomS[tid];
      #pragma unroll 8
      for (int i=0;i<64;++i) a += cm_[i]*bf2f(kcs[i*SK + tid]);
      kmomS[tid] = a;
    } else if (tid < 192){
      const int j = tid - 64;
      float a = Pmd * xmomS[j];
      #pragma unroll 8
      for (int i=0;i<64;++i) a += cm_[i]*bf2f(xbs[i*SX + j]);
      xmomS[j] = a;
    }
    __syncthreads();

    // ---- P4: g_m = X1 @ W2 - v  -> gms ----
    {
      bfrag_t a4[4];
      #pragma unroll
      for (int kt=0;kt<4;++kt) a4[kt] = *(const bfrag_t*)&xbs[(m0+lq)*SX + kt*32 + quad*8];
      #pragma unroll
      for (int nt=0;nt<4;++nt){
        facc_t z = {0.f,0.f,0.f,0.f};
        #pragma unroll
        for (int kt=0;kt<4;++kt){
          const bfrag_t bb = *(const bfrag_t*)&W2T[(nt*16+lq)*SX + kt*32 + quad*8];
          z = MFMA16(a4[kt], bb, z);
        }
        const int colc = nt*16+lq, r0w = m0 + quad*4;
        const float g0 = z[0] - bf2f(gms[(r0w+0)*SK + colc]);
        const float g1 = z[1] - bf2f(gms[(r0w+1)*SK + colc]);
        const float g2 = z[2] - bf2f(gms[(r0w+2)*SK + colc]);
        const float g3 = z[3] - bf2f(gms[(r0w+3)*SK + colc]);
        tile_store_bf16(gms32, SK/2, r0w, colc, g0, g1, g2, g3, lane);
      }
    }
    __syncthreads();

    // ---- P5: gZ1 = (g_m @ W2^T) * silu_bwd(Z1) -> xbs ----
    {
      const bfrag_t a0 = *(const bfrag_t*)&gms[(m0+lq)*SK + quad*8];
      const bfrag_t a1 = *(const bfrag_t*)&gms[(m0+lq)*SK + 32 + quad*8];
      #pragma unroll
      for (int nt=0;nt<8;++nt){
        facc_t gz = {0.f,0.f,0.f,0.f};
        const bfrag_t b0 = *(const bfrag_t*)&W2n[(nt*16+lq)*SK + quad*8];
        const bfrag_t b1 = *(const bfrag_t*)&W2n[(nt*16+lq)*SK + 32 + quad*8];
        gz = MFMA16(a0, b0, gz);
        gz = MFMA16(a1, b1, gz);
        float o[4];
        #pragma unroll
        for (int r=0;r<4;++r){
          const float zz = zk[nt][r];
          const float sg = sigf(zz);
          o[r] = gz[r] * (sg * (1.0f + zz*(1.0f - sg)));
        }
        tile_store_bf16(xbs32, SX/2, m0+quad*4, nt*16+lq, o[0], o[1], o[2], o[3], lane);
      }
    }
    __syncthreads();

    // ---- P6: w1mom / w2mom ----
    if (tid < 128){
      float a = Psd * w1momS[tid];
      #pragma unroll 8
      for (int i=0;i<64;++i) a += c1_[i]*bf2f(xbs[i*SX + tid]);
      w1momS[tid] = a;
    } else if (tid < 192){
      const int e = tid - 128;
      float a = Psd * w2momS[e];
      #pragma unroll 8
      for (int i=0;i<64;++i) a += c1_[i]*bf2f(gms[i*SK + e]);
      w2momS[e] = a;
    }
    __syncthreads();

    // ---- P7: state updates (rank-1), rebuild bf16 operand copies ----
    {
      const int j = tid >> 1, half = (tid & 1)*32;
      // W1T[j][d] = Pmd*W1T + w1mom[j]*kmom[d]
      {
        const float wm = w1momS[j];
        #pragma unroll
        for (int i=0;i<4;++i){
          const int ii = (i + j) & 3;
          const int off = j*SK + half + ii*8;
          bfrag_t wv = *(const bfrag_t*)&W1T[off];
          alignas(16) unsigned short o[8];
          #pragma unroll
          for (int s2=0;s2<8;++s2){
            const float f = Pmd * bf2f((unsigned short)wv[s2]) + wm * kmomS[half + ii*8 + s2];
            o[s2] = (unsigned short)f2bfu(f);
          }
          *(bfrag_t*)&W1T[off] = *(const bfrag_t*)o;
        }
      }
      // W2n[j][e] = Pmd*W2n + xmom[j]*w2mom[e] ; W2T rebuilt via lane-pair pack
      {
        const float xm = xmomS[j];
        alignas(16) unsigned short tb[32];
        #pragma unroll
        for (int i=0;i<4;++i){
          const int ii = (i + j) & 3;
          const int off = j*SK + half + ii*8;
          bfrag_t wv = *(const bfrag_t*)&W2n[off];
          alignas(16) unsigned short o[8];
          #pragma unroll
          for (int s2=0;s2<8;++s2){
            const float f = Pmd * bf2f((unsigned short)wv[s2]) + xm * w2momS[half + ii*8 + s2];
            o[s2] = (unsigned short)f2bfu(f);
            tb[ii*8 + s2] = o[s2];
          }
          *(bfrag_t*)&W2n[off] = *(const bfrag_t*)o;
        }
        const bool jeven = ((j & 1) == 0);
        #pragma unroll 8
        for (int e2=0;e2<32;++e2){
          const unsigned own = tb[e2];
          const unsigned part = (unsigned)__shfl_xor((int)own, 2);
          if (jeven) W2T32[(half + e2)*(SX/2) + (j>>1)] = own | (part<<16);
        }
      }
    }
    __syncthreads();

    // ---- P8: hq = silu(qc @ W1new) -> xbs ----
    {
      const bfrag_t a0 = *(const bfrag_t*)&qcs[(m0+lq)*SK + quad*8];
      const bfrag_t a1 = *(const bfrag_t*)&qcs[(m0+lq)*SK + 32 + quad*8];
      #pragma unroll
      for (int nt=0;nt<8;++nt){
        facc_t z = {0.f,0.f,0.f,0.f};
        const bfrag_t b0 = *(const bfrag_t*)&W1T[(nt*16+lq)*SK + quad*8];
        const bfrag_t b1 = *(const bfrag_t*)&W1T[(nt*16+lq)*SK + 32 + quad*8];
        z = MFMA16(a0, b0, z);
        z = MFMA16(a1, b1, z);
        tile_store_bf16(xbs32, SX/2, m0+quad*4, nt*16+lq,
                        z[0]*sigf(z[0]), z[1]*sigf(z[1]), z[2]*sigf(z[2]), z[3]*sigf(z[3]), lane);
      }
    }
    __syncthreads();

    // ---- P9: y = hq @ W2new -> out (B,H,D,L flat) ----
    {
      bfrag_t a4[4];
      #pragma unroll
      for (int kt=0;kt<4;++kt) a4[kt] = *(const bfrag_t*)&xbs[(m0+lq)*SX + kt*32 + quad*8];
      #pragma unroll
      for (int nt=0;nt<4;++nt){
        facc_t y = {0.f,0.f,0.f,0.f};
        #pragma unroll
        for (int kt=0;kt<4;++kt){
          const bfrag_t bb = *(const bfrag_t*)&W2T[(nt*16+lq)*SX + kt*32 + quad*8];
          y = MFMA16(a4[kt], bb, y);
        }
        float4 ov; ov.x = y[0]; ov.y = y[1]; ov.z = y[2]; ov.w = y[3];
        *(float4*)&out[(size_t)bh*D_*L_ + (size_t)(nt*16+lq)*L_ + l0 + m0 + quad*4] = ov;
      }
    }
    // next chunk's P1/P0 touch kcs/qcs/gms/cm_ only after the post-P1 barrier
  }
}

extern "C" void kernel_launch(void* const* d_in, const int* in_sizes, int n_in,
                              void* d_out, int out_size, void* d_ws, size_t ws_size,
                              hipStream_t stream)
{
  const float* x   = (const float*)d_in[0];
  const float* Wq  = (const float*)d_in[1];
  const float* Wk  = (const float*)d_in[2];
  const float* Wv  = (const float*)d_in[3];
  const float* cqw = (const float*)d_in[4];
  const float* cqb = (const float*)d_in[5];
  const float* ckw = (const float*)d_in[6];
  const float* ckb = (const float*)d_in[7];
  const float* cvw = (const float*)d_in[8];
  const float* cvb = (const float*)d_in[9];
  const float* qnw = (const float*)d_in[10];
  const float* knw = (const float*)d_in[11];
  const float* mdw = (const float*)d_in[12];
  const float* mdb = (const float*)d_in[13];
  const float* sw  = (const float*)d_in[14];
  const float* sb  = (const float*)d_in[15];
  const float* lw  = (const float*)d_in[16];
  const float* lb  = (const float*)d_in[17];
  const float* W1  = (const float*)d_in[18];
  const float* W2  = (const float*)d_in[19];
  float* out = (float*)d_out;

  const size_t SZ = (size_t)B_ * L_ * HID_;   // 16,777,216
  const size_t WSZ = (size_t)HID_ * HID_;     //  1,048,576
  unsigned short* xb  = (unsigned short*)d_ws;
  unsigned short* wqb = xb  + SZ;
  unsigned short* wkb = wqb + WSZ;
  unsigned short* wvb = wkb + WSZ;
  unsigned short* qb  = wvb + WSZ;
  unsigned short* kb  = qb  + SZ;
  unsigned short* vb  = kb  + SZ;
  float* gts = (float*)(vb + SZ);             // 3*B*H*L fp32

  cast_kernel<<<16384 + 3*1024, 256, 0, stream>>>(x, Wq, Wk, Wv, xb, wqb, wkb, wvb);
  dim3 gg(HID_/128, (B_*L_)/128);
  gemm_bf16_nt<<<gg, 256, 0, stream>>>(xb, wqb, qb, B_*L_, HID_, HID_);
  gemm_bf16_nt<<<gg, 256, 0, stream>>>(xb, wkb, kb, B_*L_, HID_, HID_);
  gemm_bf16_nt<<<gg, 256, 0, stream>>>(xb, wvb, vb, B_*L_, HID_, HID_);
  gates_kernel<<<(B_*L_)/64, 256, 0, stream>>>(x, mdw, mdb, sw, sb, lw, lb, gts);
  scan_kernel<<<B_*H_, 256, 0, stream>>>(qb, kb, vb, gts,
                                         cqw, cqb, ckw, ckb, cvw, cvb,
                                         qnw, knw, W1, W2, out);
}

// Round 4
// 1178.756 us; speedup vs baseline: 4.4311x; 2.4644x over previous
//
#include <hip/hip_runtime.h>

#define B_ 4
#define L_ 4096
#define HID_ 1024
#define H_ 16
#define D_ 64
#define DM_ 128
#define CS_ 64
#define NCH_ 64
#define EPS_ 1e-6f

typedef __attribute__((ext_vector_type(8))) short bfrag_t;   // 8 bf16 = 4 VGPRs
typedef __attribute__((ext_vector_type(4))) float facc_t;    // MFMA C/D

#define MFMA16(a,b,c) __builtin_amdgcn_mfma_f32_16x16x32_bf16(a,b,c,0,0,0)

__device__ __forceinline__ float sigf(float x){ return 1.0f/(1.0f + __expf(-x)); }

__device__ __forceinline__ unsigned f2bfu(float x){   // fp32 -> bf16 RNE
  unsigned u = __float_as_uint(x);
  return (u + 0x7fffu + ((u>>16)&1u)) >> 16;
}
__device__ __forceinline__ float bf2f(unsigned short s){
  return __uint_as_float(((unsigned)s)<<16);
}

// Pack-write a 16x16 MFMA C-tile (4 regs) as bf16 into LDS, pairing adjacent
// lanes so every LDS write is a full b32.
__device__ __forceinline__ void tile_store_bf16(unsigned* d32, int strideDW,
    int row0, int col, float v0, float v1, float v2, float v3, int lane){
  unsigned b0=f2bfu(v0), b1=f2bfu(v1), b2=f2bfu(v2), b3=f2bfu(v3);
  unsigned p01 = b0 | (b1<<16), p23 = b2 | (b3<<16);
  unsigned q01 = (unsigned)__shfl_xor((int)p01, 1);
  unsigned q23 = (unsigned)__shfl_xor((int)p23, 1);
  const int cd = col>>1;
  if (!(lane & 1)){
    d32[(row0+0)*strideDW + cd] = (p01 & 0xffffu) | (q01 << 16);
    d32[(row0+1)*strideDW + cd] = (p01 >> 16)     | (q01 & 0xffff0000u);
  } else {
    d32[(row0+2)*strideDW + cd] = (q23 & 0xffffu) | (p23 << 16);
    d32[(row0+3)*strideDW + cd] = (q23 >> 16)     | (p23 & 0xffff0000u);
  }
}

// ---------------------------------------------------------------------------
// cast fp32 -> bf16 for x and Wq/Wk/Wv
// ---------------------------------------------------------------------------
__global__ __launch_bounds__(256) void cast_kernel(
    const float* __restrict__ x,  const float* __restrict__ wq,
    const float* __restrict__ wk, const float* __restrict__ wv,
    unsigned short* __restrict__ xb,  unsigned short* __restrict__ wqb,
    unsigned short* __restrict__ wkb, unsigned short* __restrict__ wvb)
{
  const int bid = blockIdx.x;
  const float* s; unsigned short* d; int base;
  if (bid < 16384){ s = x; d = xb; base = bid*1024; }
  else {
    int r = bid - 16384; const int a = r >> 10; r &= 1023; base = r*1024;
    s = (a==0)?wq:(a==1)?wk:wv;
    d = (a==0)?wqb:(a==1)?wkb:wvb;
  }
  const int i = base + threadIdx.x*4;
  float4 v = *(const float4*)(s + i);
  unsigned lo = f2bfu(v.x) | (f2bfu(v.y)<<16);
  unsigned hi = f2bfu(v.z) | (f2bfu(v.w)<<16);
  uint2 o; o.x = lo; o.y = hi;
  *(uint2*)(d + i) = o;
}

// ---------------------------------------------------------------------------
// C = A @ B^T (bf16), 128x128 tile, BK=32, 16x16x32 MFMA.
// C written in HEAD-MAJOR layout: [b][h][l][d]
// ---------------------------------------------------------------------------
__global__ __launch_bounds__(256, 2) void gemm_bf16_nt(
    const unsigned short* __restrict__ A, const unsigned short* __restrict__ Bw,
    unsigned short* __restrict__ C, int M, int N, int K)
{
  __shared__ __align__(16) unsigned short As[128*32];
  __shared__ __align__(16) unsigned short Bs[128*32];
  const int tid = threadIdx.x;
  const int lane = tid & 63, wave = tid >> 6;
  const int lq = lane & 15, quad = lane >> 4;
  const int m0 = blockIdx.y*128, n0 = blockIdx.x*128;
  const int row = tid >> 2, ks = (tid & 3)*8;
  const int mo = (wave & 1)*64, no = (wave >> 1)*64;

  const unsigned short* pa0 = A  + (size_t)(m0 + row)*K + ks;
  const unsigned short* pa1 = pa0 + (size_t)64*K;
  const unsigned short* pb0 = Bw + (size_t)(n0 + row)*K + ks;
  const unsigned short* pb1 = pb0 + (size_t)64*K;

  uint4 ra0 = *(const uint4*)pa0;
  uint4 ra1 = *(const uint4*)pa1;
  uint4 rb0 = *(const uint4*)pb0;
  uint4 rb1 = *(const uint4*)pb1;

  facc_t acc[4][4];
  #pragma unroll
  for (int i=0;i<4;++i)
    #pragma unroll
    for (int j=0;j<4;++j) acc[i][j] = (facc_t){0.f,0.f,0.f,0.f};

  const int kiters = K >> 5;
  for (int kt = 0; kt < kiters; ++kt){
    *(uint4*)&As[row*32 + ks]      = ra0;
    *(uint4*)&As[(row+64)*32 + ks] = ra1;
    *(uint4*)&Bs[row*32 + ks]      = rb0;
    *(uint4*)&Bs[(row+64)*32 + ks] = rb1;
    __syncthreads();
    if (kt+1 < kiters){
      const int off = (kt+1)*32;
      ra0 = *(const uint4*)(pa0 + off);
      ra1 = *(const uint4*)(pa1 + off);
      rb0 = *(const uint4*)(pb0 + off);
      rb1 = *(const uint4*)(pb1 + off);
    }
    bfrag_t af[4], bf[4];
    #pragma unroll
    for (int mt=0;mt<4;++mt) af[mt] = *(const bfrag_t*)&As[(mo+mt*16+lq)*32 + quad*8];
    #pragma unroll
    for (int nt=0;nt<4;++nt) bf[nt] = *(const bfrag_t*)&Bs[(no+nt*16+lq)*32 + quad*8];
    #pragma unroll
    for (int mt=0;mt<4;++mt)
      #pragma unroll
      for (int nt=0;nt<4;++nt)
        acc[mt][nt] = MFMA16(af[mt], bf[nt], acc[mt][nt]);
    __syncthreads();
  }

  #pragma unroll
  for (int mt=0;mt<4;++mt)
    #pragma unroll
    for (int nt=0;nt<4;++nt)
      #pragma unroll
      for (int r=0;r<4;++r){
        const int rr = m0 + mo + mt*16 + quad*4 + r;
        const int cc = n0 + no + nt*16 + lq;
        C[((size_t)((rr>>12)*16 + (cc>>6))*L_ + (rr&4095))*64 + (cc&63)]
            = (unsigned short)f2bfu(acc[mt][nt][r]);
      }
}

// ---------------------------------------------------------------------------
// Gate logits + per-chunk suffix products. Each block = one (b, chunk).
// ---------------------------------------------------------------------------
__global__ __launch_bounds__(256, 2) void gates_kernel(
  const float* __restrict__ x,
  const float* __restrict__ mdw, const float* __restrict__ mdb,
  const float* __restrict__ sw,  const float* __restrict__ sb,
  const float* __restrict__ lw,  const float* __restrict__ lb,
  float* __restrict__ cmb, float* __restrict__ c1b, float* __restrict__ ppb)
{
  __shared__ float xs[64][68];
  __shared__ float wg[48][68];
  const int tid = threadIdx.x;
  const int m0 = blockIdx.x * 64;
  const int tx = tid & 15, ty = tid >> 4;
  float acc[4][3];
  #pragma unroll
  for (int r=0;r<4;++r){ acc[r][0]=0.f; acc[r][1]=0.f; acc[r][2]=0.f; }

  for (int k0 = 0; k0 < HID_; k0 += 64){
    {
      const int r = tid >> 2, kq = tid & 3;
      const float* xp = x + (size_t)(m0 + r) * HID_ + k0 + kq*16;
      #pragma unroll
      for (int u=0;u<4;++u){
        float4 v = *(const float4*)(xp + u*4);
        *(float4*)&xs[r][kq*16 + u*4] = v;
      }
    }
    #pragma unroll
    for (int u=0;u<3;++u){
      const int idx = tid + 256*u;
      const int gi = idx >> 4, q = idx & 15;
      const float* wp = (gi < 16) ? (mdw + (size_t)gi*HID_)
                      : (gi < 32) ? (sw  + (size_t)(gi-16)*HID_)
                                  : (lw  + (size_t)(gi-32)*HID_);
      float4 v = *(const float4*)(wp + k0 + q*4);
      *(float4*)&wg[gi][q*4] = v;
    }
    __syncthreads();
    for (int kk=0; kk<64; ++kk){
      float xv[4], wv[3];
      #pragma unroll
      for (int r=0;r<4;++r) xv[r] = xs[ty*4+r][kk];
      #pragma unroll
      for (int gg=0;gg<3;++gg) wv[gg] = wg[tx*3+gg][kk];
      #pragma unroll
      for (int r=0;r<4;++r)
        #pragma unroll
        for (int gg=0;gg<3;++gg) acc[r][gg] += xv[r]*wv[gg];
    }
    __syncthreads();
  }

  float (*ls)[68] = xs;
  #pragma unroll
  for (int gg=0; gg<3; ++gg){
    const int gi = tx*3 + gg;
    const int s = gi >> 4, hh = gi & 15;
    const float bias = (s==0) ? mdb[hh] : (s==1) ? sb[hh] : lb[hh];
    #pragma unroll
    for (int r=0;r<4;++r) ls[gi][ty*4+r] = acc[r][gg] + bias;
  }
  __syncthreads();

  const int lane = tid & 63, wv2 = tid >> 6;
  const int b = m0 >> 12, n = (m0 & 4095) >> 6;
  #pragma unroll
  for (int u=0;u<4;++u){
    const int hh = wv2*4 + u;
    const float md = 1.0f - sigf(ls[hh][lane]);
    const float sd = sigf(ls[16+hh][lane]);
    const float lr = sigf(ls[32+hh][lane]);
    float vm = md, vs = sd;
    #pragma unroll
    for (int off = 1; off < 64; off <<= 1){
      float om = __shfl_down(vm, off);
      float os = __shfl_down(vs, off);
      if (lane + off < 64){ vm *= om; vs *= os; }
    }
    float mex = __shfl_down(vm, 1);
    float sex = __shfl_down(vs, 1);
    if (lane == 63){ mex = 1.0f; sex = 1.0f; }
    const size_t base = ((size_t)(b*16 + hh)*NCH_ + n)*64;
    cmb[base + lane] = mex;
    c1b[base + lane] = -lr * sex;
    if (lane == 0){
      ppb[((size_t)(b*16+hh)*NCH_ + n)*2 + 0] = vm;
      ppb[((size_t)(b*16+hh)*NCH_ + n)*2 + 1] = vs;
    }
  }
}

// ---------------------------------------------------------------------------
// MFMA chunk scan, 512 threads (8 waves). Staging software-pipelined one
// chunk ahead into double-buffered LDS; gate coefficients precomputed.
// ---------------------------------------------------------------------------
#define SK 80    // stride (bf16) of 64-wide arrays
#define SX 144   // stride (bf16) of 128-wide arrays

__global__ __launch_bounds__(512, 1) void scan_kernel(
  const unsigned short* __restrict__ qg, const unsigned short* __restrict__ kg,
  const unsigned short* __restrict__ vg,
  const float* __restrict__ cmg, const float* __restrict__ c1g,
  const float* __restrict__ ppg,
  const float* __restrict__ cqw, const float* __restrict__ cqb,
  const float* __restrict__ ckw, const float* __restrict__ ckb,
  const float* __restrict__ cvw, const float* __restrict__ cvb,
  const float* __restrict__ qnw, const float* __restrict__ knw,
  const float* __restrict__ W1in, const float* __restrict__ W2in,
  float* __restrict__ out)
{
  const int bh = blockIdx.x;
  const int h = bh & 15;
  const int tid = threadIdx.x;
  const int lane = tid & 63, wave = tid >> 6;
  const int lq = lane & 15, quad = lane >> 4;
  const int rw = (wave & 3) * 16;
  const int cw = wave >> 2;

  __shared__ __align__(16) unsigned short sm[69632];
  // buffer s (0/1): kcs = sm + s*5120, qcs = sm+10240 + s*5120, gms = sm+20480 + s*5120
  unsigned short* xbs = sm + 30720;   // [64][SX]
  unsigned short* W1T = sm + 39936;   // [128][SK]  W1^T (k=d contiguous)
  unsigned short* W2n = sm + 50176;   // [128][SK]  W2 [j][e]
  unsigned short* W2T = sm + 60416;   // [64][SX]   W2^T [e][j]
  __shared__ float cmA[2][64], c1A[2][64], ppS[2][2];
  __shared__ float kmomS[64], xmomS[128], w1momS[128], w2momS[64];

  // ---- init state ----
  {
    const int j = tid >> 2, q0 = (tid & 3) * 16;
    const float* w1p = W1in + (size_t)h * D_ * DM_;
    #pragma unroll 4
    for (int t=0;t<16;++t)
      W1T[j*SK + q0 + t] = (unsigned short)f2bfu(w1p[(size_t)(q0+t)*DM_ + j]);
    const float* w2p = W2in + (size_t)h * DM_ * D_ + (size_t)j*D_ + q0;
    #pragma unroll 4
    for (int t=0;t<16;++t){
      unsigned short v = (unsigned short)f2bfu(w2p[t]);
      W2n[j*SK + q0 + t] = v;
      W2T[(q0+t)*SX + j] = v;
    }
  }
  if (tid < 64){ kmomS[tid]=0.f; w2momS[tid]=0.f; }
  if (tid < 128){ xmomS[tid]=0.f; w1momS[tid]=0.f; }

  const int c = h*64 + lane;
  float wkc[4], wqc[4], wvc[4];
  #pragma unroll
  for (int kk=0;kk<4;++kk){ wkc[kk]=ckw[c*4+kk]; wqc[kk]=cqw[c*4+kk]; wvc[kk]=cvw[c*4+kk]; }
  const float bkc = ckb[c], bqc = cqb[c], bvc = cvb[c];
  const float knf = knw[lane], qnf = qnw[lane];
  const long hbase = (long)bh * L_ * 64 + lane;   // head-major, col=lane

  // staging registers (window of 11 raw rows for this wave's 8 output rows)
  float rk[11], rq[11], rv[11];
  float cmr=0.f, c1r=0.f, ppr=0.f;

  auto stage_load = [&](int m){
    if (m >= NCH_) return;
    const int i0 = wave*8;
    const long sb = hbase + (long)(m*64 + i0)*64;
    #pragma unroll
    for (int t=0;t<11;++t){
      const bool ok = (m*64 + i0 + t - 3) >= 0;
      const long a = sb + (long)(t-3)*64;
      rk[t] = ok ? bf2f(kg[a]) : 0.f;
      rq[t] = ok ? bf2f(qg[a]) : 0.f;
      rv[t] = ok ? bf2f(vg[a]) : 0.f;
    }
    if (wave == 0){
      cmr = cmg[((size_t)bh*NCH_ + m)*64 + lane];
      c1r = c1g[((size_t)bh*NCH_ + m)*64 + lane];
    }
    if (tid < 2) ppr = ppg[((size_t)bh*NCH_ + m)*2 + tid];
  };

  auto stage_compute = [&](int m, int s){
    if (m >= NCH_) return;
    const int i0 = wave*8;
    unsigned* k32 = (unsigned*)(sm + s*5120);
    unsigned* q32 = (unsigned*)(sm + 10240 + s*5120);
    unsigned* g32 = (unsigned*)(sm + 20480 + s*5120);
    #pragma unroll
    for (int i=0;i<8;++i){
      float ak = bkc + wkc[0]*rk[i] + wkc[1]*rk[i+1] + wkc[2]*rk[i+2] + wkc[3]*rk[i+3];
      float aq = bqc + wqc[0]*rq[i] + wqc[1]*rq[i+1] + wqc[2]*rq[i+2] + wqc[3]*rq[i+3];
      float av = bvc + wvc[0]*rv[i] + wvc[1]*rv[i+1] + wvc[2]*rv[i+2] + wvc[3]*rv[i+3];
      const float yk = ak*sigf(ak), yq = aq*sigf(aq), yv = av*sigf(av);
      float ssk = yk*yk, ssq = yq*yq;
      #pragma unroll
      for (int o2=32;o2>=1;o2>>=1){ ssk += __shfl_xor(ssk,o2); ssq += __shfl_xor(ssq,o2); }
      const float vk = knf * yk * rsqrtf(ssk*(1.0f/64.0f) + EPS_);
      const float vq = qnf * yq * rsqrtf(ssq*(1.0f/64.0f) + EPS_);
      unsigned bk = f2bfu(vk), bq = f2bfu(vq), bv = f2bfu(yv);
      unsigned pk = (unsigned)__shfl_xor((int)bk,1);
      unsigned pq = (unsigned)__shfl_xor((int)bq,1);
      unsigned pv = (unsigned)__shfl_xor((int)bv,1);
      if (!(lane & 1)){
        const int dw = (i0+i)*(SK/2) + (lane>>1);
        k32[dw] = bk | (pk<<16);
        q32[dw] = bq | (pq<<16);
        g32[dw] = bv | (pv<<16);
      }
    }
    if (wave == 0){ cmA[s][lane] = cmr; c1A[s][lane] = c1r; }
    if (tid < 2) ppS[s][tid] = ppr;
  };

  // prologue: stage chunk 0
  stage_load(0);
  stage_compute(0, 0);
  __syncthreads();

  for (int n = 0; n < NCH_; ++n){
    const int cur = n & 1, nxt = cur ^ 1;
    const unsigned short* kcs = sm + cur*5120;
    const unsigned short* qcs = sm + 10240 + cur*5120;
    unsigned short* gms = sm + 20480 + cur*5120;

    stage_load(n+1);   // global loads issue here; latency hides under P2

    // ---- P2: Z1 = kc @ W1 ; X1 = silu(Z1) -> xbs ----
    facc_t zk[4];
    {
      const bfrag_t a0 = *(const bfrag_t*)&kcs[(rw+lq)*SK + quad*8];
      const bfrag_t a1 = *(const bfrag_t*)&kcs[(rw+lq)*SK + 32 + quad*8];
      #pragma unroll
      for (int nt=0;nt<4;++nt){
        const int j = cw*64 + nt*16 + lq;
        const bfrag_t b0 = *(const bfrag_t*)&W1T[j*SK + quad*8];
        const bfrag_t b1 = *(const bfrag_t*)&W1T[j*SK + 32 + quad*8];
        facc_t z = {0.f,0.f,0.f,0.f};
        z = MFMA16(a0,b0,z); z = MFMA16(a1,b1,z);
        zk[nt] = z;
        tile_store_bf16((unsigned*)xbs, SX/2, rw+quad*4, j,
          z[0]*sigf(z[0]), z[1]*sigf(z[1]), z[2]*sigf(z[2]), z[3]*sigf(z[3]), lane);
      }
    }
    __syncthreads();   // b1

    // ---- P4: g_m = X1 @ W2 - v (in gms) ; P3: kmom/xmom ; stage compute ----
    {
      bfrag_t xa[4];
      #pragma unroll
      for (int kt=0;kt<4;++kt) xa[kt] = *(const bfrag_t*)&xbs[(rw+lq)*SX + kt*32 + quad*8];
      #pragma unroll
      for (int nt=0;nt<2;++nt){
        const int e = cw*32 + nt*16 + lq;
        facc_t z = {0.f,0.f,0.f,0.f};
        #pragma unroll
        for (int kt=0;kt<4;++kt){
          const bfrag_t bb = *(const bfrag_t*)&W2T[e*SX + kt*32 + quad*8];
          z = MFMA16(xa[kt], bb, z);
        }
        const int r0 = rw + quad*4;
        const float g0 = z[0] - bf2f(gms[(r0+0)*SK + e]);
        const float g1 = z[1] - bf2f(gms[(r0+1)*SK + e]);
        const float g2 = z[2] - bf2f(gms[(r0+2)*SK + e]);
        const float g3 = z[3] - bf2f(gms[(r0+3)*SK + e]);
        tile_store_bf16((unsigned*)gms, SK/2, r0, e, g0,g1,g2,g3, lane);
      }
    }
    if (tid < 64){
      float a = ppS[cur][0] * kmomS[tid];
      #pragma unroll 8
      for (int i=0;i<64;++i) a += cmA[cur][i]*bf2f(kcs[i*SK + tid]);
      kmomS[tid] = a;
    } else if (tid < 192){
      const int j = tid - 64;
      float a = ppS[cur][0] * xmomS[j];
      #pragma unroll 8
      for (int i=0;i<64;++i) a += cmA[cur][i]*bf2f(xbs[i*SX + j]);
      xmomS[j] = a;
    }
    stage_compute(n+1, nxt);
    __syncthreads();   // b2

    // ---- P5: gZ1 = (g_m @ W2) * silu_bwd(Z1) -> xbs ----
    {
      const bfrag_t a0 = *(const bfrag_t*)&gms[(rw+lq)*SK + quad*8];
      const bfrag_t a1 = *(const bfrag_t*)&gms[(rw+lq)*SK + 32 + quad*8];
      #pragma unroll
      for (int nt=0;nt<4;++nt){
        const int j = cw*64 + nt*16 + lq;
        const bfrag_t b0 = *(const bfrag_t*)&W2n[j*SK + quad*8];
        const bfrag_t b1 = *(const bfrag_t*)&W2n[j*SK + 32 + quad*8];
        facc_t gz = {0.f,0.f,0.f,0.f};
        gz = MFMA16(a0,b0,gz); gz = MFMA16(a1,b1,gz);
        float o[4];
        #pragma unroll
        for (int r=0;r<4;++r){
          const float zz = zk[nt][r];
          const float sg = sigf(zz);
          o[r] = gz[r] * (sg * (1.0f + zz*(1.0f - sg)));
        }
        tile_store_bf16((unsigned*)xbs, SX/2, rw+quad*4, j, o[0],o[1],o[2],o[3], lane);
      }
    }
    __syncthreads();   // b3

    // ---- P6: w1mom / w2mom ----
    if (tid < 128){
      float a = ppS[cur][1] * w1momS[tid];
      #pragma unroll 8
      for (int i=0;i<64;++i) a += c1A[cur][i]*bf2f(xbs[i*SX + tid]);
      w1momS[tid] = a;
    } else if (tid < 192){
      const int e = tid - 128;
      float a = ppS[cur][1] * w2momS[e];
      #pragma unroll 8
      for (int i=0;i<64;++i) a += c1A[cur][i]*bf2f(gms[i*SK + e]);
      w2momS[e] = a;
    }
    __syncthreads();   // b4

    // ---- P7: rank-1 state updates (W1T, W2n, W2T independently RMW) ----
    {
      const float Pmd = ppS[cur][0];
      const int j = tid >> 2, q0 = (tid & 3)*16;
      const float wm = w1momS[j], xm = xmomS[j];
      #pragma unroll
      for (int half=0; half<16; half+=8){
        const int off = j*SK + q0 + half;
        bfrag_t wv = *(const bfrag_t*)&W1T[off];
        alignas(16) unsigned short o[8];
        #pragma unroll
        for (int s2=0;s2<8;++s2)
          o[s2] = (unsigned short)f2bfu(Pmd*bf2f((unsigned short)wv[s2]) + wm*kmomS[q0+half+s2]);
        *(bfrag_t*)&W1T[off] = *(const bfrag_t*)o;
      }
      #pragma unroll
      for (int half=0; half<16; half+=8){
        const int off = j*SK + q0 + half;
        bfrag_t wv = *(const bfrag_t*)&W2n[off];
        alignas(16) unsigned short o[8];
        #pragma unroll
        for (int s2=0;s2<8;++s2)
          o[s2] = (unsigned short)f2bfu(Pmd*bf2f((unsigned short)wv[s2]) + xm*w2momS[q0+half+s2]);
        *(bfrag_t*)&W2n[off] = *(const bfrag_t*)o;
      }
      const int e2 = tid >> 3, js = (tid & 7)*16;
      const float w2m = w2momS[e2];
      #pragma unroll
      for (int half=0; half<16; half+=8){
        const int off = e2*SX + js + half;
        bfrag_t wv = *(const bfrag_t*)&W2T[off];
        alignas(16) unsigned short o[8];
        #pragma unroll
        for (int s2=0;s2<8;++s2)
          o[s2] = (unsigned short)f2bfu(Pmd*bf2f((unsigned short)wv[s2]) + xmomS[js+half+s2]*w2m);
        *(bfrag_t*)&W2T[off] = *(const bfrag_t*)o;
      }
    }
    __syncthreads();   // b5

    // ---- P8: hq = silu(qc @ W1new) -> xbs ----
    {
      const bfrag_t a0 = *(const bfrag_t*)&qcs[(rw+lq)*SK + quad*8];
      const bfrag_t a1 = *(const bfrag_t*)&qcs[(rw+lq)*SK + 32 + quad*8];
      #pragma unroll
      for (int nt=0;nt<4;++nt){
        const int j = cw*64 + nt*16 + lq;
        const bfrag_t b0 = *(const bfrag_t*)&W1T[j*SK + quad*8];
        const bfrag_t b1 = *(const bfrag_t*)&W1T[j*SK + 32 + quad*8];
        facc_t z = {0.f,0.f,0.f,0.f};
        z = MFMA16(a0,b0,z); z = MFMA16(a1,b1,z);
        tile_store_bf16((unsigned*)xbs, SX/2, rw+quad*4, j,
          z[0]*sigf(z[0]), z[1]*sigf(z[1]), z[2]*sigf(z[2]), z[3]*sigf(z[3]), lane);
      }
    }
    __syncthreads();   // b6

    // ---- P9: y = hq @ W2new -> out (B,H,D,L flat) ----
    {
      bfrag_t xa[4];
      #pragma unroll
      for (int kt=0;kt<4;++kt) xa[kt] = *(const bfrag_t*)&xbs[(rw+lq)*SX + kt*32 + quad*8];
      #pragma unroll
      for (int nt=0;nt<2;++nt){
        const int e = cw*32 + nt*16 + lq;
        facc_t y = {0.f,0.f,0.f,0.f};
        #pragma unroll
        for (int kt=0;kt<4;++kt){
          const bfrag_t bb = *(const bfrag_t*)&W2T[e*SX + kt*32 + quad*8];
          y = MFMA16(xa[kt], bb, y);
        }
        float4 ov; ov.x = y[0]; ov.y = y[1]; ov.z = y[2]; ov.w = y[3];
        *(float4*)&out[(size_t)bh*D_*L_ + (size_t)e*L_ + n*64 + rw + quad*4] = ov;
      }
    }
    __syncthreads();   // b7: staging of n+1 visible; xbs reusable
  }
}

extern "C" void kernel_launch(void* const* d_in, const int* in_sizes, int n_in,
                              void* d_out, int out_size, void* d_ws, size_t ws_size,
                              hipStream_t stream)
{
  const float* x   = (const float*)d_in[0];
  const float* Wq  = (const float*)d_in[1];
  const float* Wk  = (const float*)d_in[2];
  const float* Wv  = (const float*)d_in[3];
  const float* cqw = (const float*)d_in[4];
  const float* cqb = (const float*)d_in[5];
  const float* ckw = (const float*)d_in[6];
  const float* ckb = (const float*)d_in[7];
  const float* cvw = (const float*)d_in[8];
  const float* cvb = (const float*)d_in[9];
  const float* qnw = (const float*)d_in[10];
  const float* knw = (const float*)d_in[11];
  const float* mdw = (const float*)d_in[12];
  const float* mdb = (const float*)d_in[13];
  const float* sw  = (const float*)d_in[14];
  const float* sb  = (const float*)d_in[15];
  const float* lw  = (const float*)d_in[16];
  const float* lb  = (const float*)d_in[17];
  const float* W1  = (const float*)d_in[18];
  const float* W2  = (const float*)d_in[19];
  float* out = (float*)d_out;

  const size_t SZ  = (size_t)B_ * L_ * HID_;   // 16,777,216
  const size_t WSZ = (size_t)HID_ * HID_;      //  1,048,576
  unsigned short* xb  = (unsigned short*)d_ws;
  unsigned short* wqb = xb  + SZ;
  unsigned short* wkb = wqb + WSZ;
  unsigned short* wvb = wkb + WSZ;
  unsigned short* qb  = wvb + WSZ;   // head-major bf16
  unsigned short* kb  = qb  + SZ;
  unsigned short* vb  = kb  + SZ;
  float* cmb = (float*)(vb + SZ);              // B*H*NCH*64
  float* c1b = cmb + (size_t)B_*H_*NCH_*64;
  float* ppb = c1b + (size_t)B_*H_*NCH_*64;    // B*H*NCH*2

  cast_kernel<<<16384 + 3*1024, 256, 0, stream>>>(x, Wq, Wk, Wv, xb, wqb, wkb, wvb);
  dim3 gg(HID_/128, (B_*L_)/128);
  gemm_bf16_nt<<<gg, 256, 0, stream>>>(xb, wqb, qb, B_*L_, HID_, HID_);
  gemm_bf16_nt<<<gg, 256, 0, stream>>>(xb, wkb, kb, B_*L_, HID_, HID_);
  gemm_bf16_nt<<<gg, 256, 0, stream>>>(xb, wvb, vb, B_*L_, HID_, HID_);
  gates_kernel<<<(B_*L_)/64, 256, 0, stream>>>(x, mdw, mdb, sw, sb, lw, lb, cmb, c1b, ppb);
  scan_kernel<<<B_*H_, 512, 0, stream>>>(qb, kb, vb, cmb, c1b, ppb,
                                         cqw, cqb, ckw, ckb, cvw, cvb,
                                         qnw, knw, W1, W2, out);
}

// Round 5
// 1012.540 us; speedup vs baseline: 5.1585x; 1.1642x over previous
//
#include <hip/hip_runtime.h>

#define B_ 4
#define L_ 4096
#define HID_ 1024
#define H_ 16
#define D_ 64
#define DM_ 128
#define CS_ 64
#define NCH_ 64
#define EPS_ 1e-6f

typedef __attribute__((ext_vector_type(8))) short bfrag_t;   // 8 bf16 = 4 VGPRs
typedef __attribute__((ext_vector_type(4))) float facc_t;    // MFMA C/D

#define MFMA16(a,b,c) __builtin_amdgcn_mfma_f32_16x16x32_bf16(a,b,c,0,0,0)

__device__ __forceinline__ float sigf(float x){ return 1.0f/(1.0f + __expf(-x)); }

__device__ __forceinline__ unsigned f2bfu(float x){   // fp32 -> bf16 RNE
  unsigned u = __float_as_uint(x);
  return (u + 0x7fffu + ((u>>16)&1u)) >> 16;
}
__device__ __forceinline__ float bf2f(unsigned short s){
  return __uint_as_float(((unsigned)s)<<16);
}

// wave64 sum via DPP row_shr prefix (VALU-speed) + readlane combine.
// No ds_swizzle: ~10x lower latency than __shfl_xor trees on CDNA.
#define DPP_ADD_(x, ctrl) x += __int_as_float(__builtin_amdgcn_update_dpp(0, __float_as_int(x), ctrl, 0xf, 0xf, true))
__device__ __forceinline__ float wsum64(float x){
  DPP_ADD_(x, 0x111);   // row_shr:1
  DPP_ADD_(x, 0x112);   // row_shr:2
  DPP_ADD_(x, 0x114);   // row_shr:4
  DPP_ADD_(x, 0x118);   // row_shr:8  -> lane 15/31/47/63 hold 16-lane sums
  const float a = __int_as_float(__builtin_amdgcn_readlane(__float_as_int(x), 15));
  const float b = __int_as_float(__builtin_amdgcn_readlane(__float_as_int(x), 31));
  const float c = __int_as_float(__builtin_amdgcn_readlane(__float_as_int(x), 47));
  const float d = __int_as_float(__builtin_amdgcn_readlane(__float_as_int(x), 63));
  return (a+b)+(c+d);
}

// ---------------------------------------------------------------------------
// cast fp32 -> bf16 for x and Wq/Wk/Wv
// ---------------------------------------------------------------------------
__global__ __launch_bounds__(256) void cast_kernel(
    const float* __restrict__ x,  const float* __restrict__ wq,
    const float* __restrict__ wk, const float* __restrict__ wv,
    unsigned short* __restrict__ xb,  unsigned short* __restrict__ wqb,
    unsigned short* __restrict__ wkb, unsigned short* __restrict__ wvb)
{
  const int bid = blockIdx.x;
  const float* s; unsigned short* d; int base;
  if (bid < 16384){ s = x; d = xb; base = bid*1024; }
  else {
    int r = bid - 16384; const int a = r >> 10; r &= 1023; base = r*1024;
    s = (a==0)?wq:(a==1)?wk:wv;
    d = (a==0)?wqb:(a==1)?wkb:wvb;
  }
  const int i = base + threadIdx.x*4;
  float4 v = *(const float4*)(s + i);
  unsigned lo = f2bfu(v.x) | (f2bfu(v.y)<<16);
  unsigned hi = f2bfu(v.z) | (f2bfu(v.w)<<16);
  uint2 o; o.x = lo; o.y = hi;
  *(uint2*)(d + i) = o;
}

// ---------------------------------------------------------------------------
// Fused QKV GEMM: C = A[16384,1024] @ Wcat[3072,1024]^T, 128x128 tile, BK=32.
// Wq/Wk/Wv contiguous -> one launch. C written head-major per tensor:
// dst[((t*B + b)*H + h)*L + l)*64 + d]
// ---------------------------------------------------------------------------
__global__ __launch_bounds__(256, 2) void gemm_bf16_nt(
    const unsigned short* __restrict__ A, const unsigned short* __restrict__ Bw,
    unsigned short* __restrict__ C, int M, int N, int K)
{
  __shared__ __align__(16) unsigned short As[128*32];
  __shared__ __align__(16) unsigned short Bs[128*32];
  const int tid = threadIdx.x;
  const int lane = tid & 63, wave = tid >> 6;
  const int lq = lane & 15, quad = lane >> 4;
  const int m0 = blockIdx.y*128, n0 = blockIdx.x*128;
  const int row = tid >> 2, ks = (tid & 3)*8;
  const int mo = (wave & 1)*64, no = (wave >> 1)*64;

  const unsigned short* pa0 = A  + (size_t)(m0 + row)*K + ks;
  const unsigned short* pa1 = pa0 + (size_t)64*K;
  const unsigned short* pb0 = Bw + (size_t)(n0 + row)*K + ks;
  const unsigned short* pb1 = pb0 + (size_t)64*K;

  uint4 ra0 = *(const uint4*)pa0;
  uint4 ra1 = *(const uint4*)pa1;
  uint4 rb0 = *(const uint4*)pb0;
  uint4 rb1 = *(const uint4*)pb1;

  facc_t acc[4][4];
  #pragma unroll
  for (int i=0;i<4;++i)
    #pragma unroll
    for (int j=0;j<4;++j) acc[i][j] = (facc_t){0.f,0.f,0.f,0.f};

  const int kiters = K >> 5;
  for (int kt = 0; kt < kiters; ++kt){
    *(uint4*)&As[row*32 + ks]      = ra0;
    *(uint4*)&As[(row+64)*32 + ks] = ra1;
    *(uint4*)&Bs[row*32 + ks]      = rb0;
    *(uint4*)&Bs[(row+64)*32 + ks] = rb1;
    __syncthreads();
    if (kt+1 < kiters){
      const int off = (kt+1)*32;
      ra0 = *(const uint4*)(pa0 + off);
      ra1 = *(const uint4*)(pa1 + off);
      rb0 = *(const uint4*)(pb0 + off);
      rb1 = *(const uint4*)(pb1 + off);
    }
    bfrag_t af[4], bf[4];
    #pragma unroll
    for (int mt=0;mt<4;++mt) af[mt] = *(const bfrag_t*)&As[(mo+mt*16+lq)*32 + quad*8];
    #pragma unroll
    for (int nt=0;nt<4;++nt) bf[nt] = *(const bfrag_t*)&Bs[(no+nt*16+lq)*32 + quad*8];
    #pragma unroll
    for (int mt=0;mt<4;++mt)
      #pragma unroll
      for (int nt=0;nt<4;++nt)
        acc[mt][nt] = MFMA16(af[mt], bf[nt], acc[mt][nt]);
    __syncthreads();
  }

  #pragma unroll
  for (int mt=0;mt<4;++mt)
    #pragma unroll
    for (int nt=0;nt<4;++nt)
      #pragma unroll
      for (int r=0;r<4;++r){
        const int rr = m0 + mo + mt*16 + quad*4 + r;
        const int cc = n0 + no + nt*16 + lq;     // 0..3071
        const int t = cc >> 10, hh = (cc >> 6) & 15, dd = cc & 63;
        const int b = rr >> 12, l = rr & 4095;
        C[((((size_t)t*B_ + b)*H_ + hh)*L_ + l)*64 + dd]
            = (unsigned short)f2bfu(acc[mt][nt][r]);
      }
}

// ---------------------------------------------------------------------------
// Gate logits + per-chunk suffix products. Each block = one (b, chunk).
// ---------------------------------------------------------------------------
__global__ __launch_bounds__(256, 2) void gates_kernel(
  const float* __restrict__ x,
  const float* __restrict__ mdw, const float* __restrict__ mdb,
  const float* __restrict__ sw,  const float* __restrict__ sb,
  const float* __restrict__ lw,  const float* __restrict__ lb,
  float* __restrict__ cmb, float* __restrict__ c1b, float* __restrict__ ppb)
{
  __shared__ float xs[64][68];
  __shared__ float wg[48][68];
  const int tid = threadIdx.x;
  const int m0 = blockIdx.x * 64;
  const int tx = tid & 15, ty = tid >> 4;
  float acc[4][3];
  #pragma unroll
  for (int r=0;r<4;++r){ acc[r][0]=0.f; acc[r][1]=0.f; acc[r][2]=0.f; }

  for (int k0 = 0; k0 < HID_; k0 += 64){
    {
      const int r = tid >> 2, kq = tid & 3;
      const float* xp = x + (size_t)(m0 + r) * HID_ + k0 + kq*16;
      #pragma unroll
      for (int u=0;u<4;++u){
        float4 v = *(const float4*)(xp + u*4);
        *(float4*)&xs[r][kq*16 + u*4] = v;
      }
    }
    #pragma unroll
    for (int u=0;u<3;++u){
      const int idx = tid + 256*u;
      const int gi = idx >> 4, q = idx & 15;
      const float* wp = (gi < 16) ? (mdw + (size_t)gi*HID_)
                      : (gi < 32) ? (sw  + (size_t)(gi-16)*HID_)
                                  : (lw  + (size_t)(gi-32)*HID_);
      float4 v = *(const float4*)(wp + k0 + q*4);
      *(float4*)&wg[gi][q*4] = v;
    }
    __syncthreads();
    for (int kk=0; kk<64; ++kk){
      float xv[4], wv[3];
      #pragma unroll
      for (int r=0;r<4;++r) xv[r] = xs[ty*4+r][kk];
      #pragma unroll
      for (int gg=0;gg<3;++gg) wv[gg] = wg[tx*3+gg][kk];
      #pragma unroll
      for (int r=0;r<4;++r)
        #pragma unroll
        for (int gg=0;gg<3;++gg) acc[r][gg] += xv[r]*wv[gg];
    }
    __syncthreads();
  }

  float (*ls)[68] = xs;
  #pragma unroll
  for (int gg=0; gg<3; ++gg){
    const int gi = tx*3 + gg;
    const int s = gi >> 4, hh = gi & 15;
    const float bias = (s==0) ? mdb[hh] : (s==1) ? sb[hh] : lb[hh];
    #pragma unroll
    for (int r=0;r<4;++r) ls[gi][ty*4+r] = acc[r][gg] + bias;
  }
  __syncthreads();

  const int lane = tid & 63, wv2 = tid >> 6;
  const int b = m0 >> 12, n = (m0 & 4095) >> 6;
  #pragma unroll
  for (int u=0;u<4;++u){
    const int hh = wv2*4 + u;
    const float md = 1.0f - sigf(ls[hh][lane]);
    const float sd = sigf(ls[16+hh][lane]);
    const float lr = sigf(ls[32+hh][lane]);
    float vm = md, vs = sd;
    #pragma unroll
    for (int off = 1; off < 64; off <<= 1){
      float om = __shfl_down(vm, off);
      float os = __shfl_down(vs, off);
      if (lane + off < 64){ vm *= om; vs *= os; }
    }
    float mex = __shfl_down(vm, 1);
    float sex = __shfl_down(vs, 1);
    if (lane == 63){ mex = 1.0f; sex = 1.0f; }
    const size_t base = ((size_t)(b*16 + hh)*NCH_ + n)*64;
    cmb[base + lane] = mex;
    c1b[base + lane] = -lr * sex;
    if (lane == 0){
      ppb[((size_t)(b*16+hh)*NCH_ + n)*2 + 0] = vm;
      ppb[((size_t)(b*16+hh)*NCH_ + n)*2 + 1] = vs;
    }
  }
}

// ---------------------------------------------------------------------------
// MFMA chunk scan, 512 threads (8 waves). DPP reductions (no ds_swizzle),
// direct b16 LDS stores, strides 72/136 u16 (4 mod 32 dw -> uniform banks).
// ---------------------------------------------------------------------------
#define SK 72    // stride (u16) of 64-wide arrays  (36 dw == 4 mod 32)
#define SX 136   // stride (u16) of 128-wide arrays (68 dw == 4 mod 32)

__global__ __launch_bounds__(512, 1) void scan_kernel(
  const unsigned short* __restrict__ qg, const unsigned short* __restrict__ kg,
  const unsigned short* __restrict__ vg,
  const float* __restrict__ cmg, const float* __restrict__ c1g,
  const float* __restrict__ ppg,
  const float* __restrict__ cqw, const float* __restrict__ cqb,
  const float* __restrict__ ckw, const float* __restrict__ ckb,
  const float* __restrict__ cvw, const float* __restrict__ cvb,
  const float* __restrict__ qnw, const float* __restrict__ knw,
  const float* __restrict__ W1in, const float* __restrict__ W2in,
  float* __restrict__ out)
{
  const int bh = blockIdx.x;
  const int h = bh & 15;
  const int tid = threadIdx.x;
  const int lane = tid & 63, wave = tid >> 6;
  const int lq = lane & 15, quad = lane >> 4;
  const int rw = (wave & 3) * 16;
  const int cw = wave >> 2;

  // u16 offsets: kcs s: s*4608; qcs: 9216+s*4608; gms: 18432+s*4608;
  // xbs: 27648; W1T: 36352; W2n: 45568; W2T: 54784; end 63488 (127 KB)
  __shared__ __align__(16) unsigned short sm[63488];
  unsigned short* xbs = sm + 27648;   // [64][SX]
  unsigned short* W1T = sm + 36352;   // [128][SK]  W1^T (k=d contiguous)
  unsigned short* W2n = sm + 45568;   // [128][SK]  W2 [j][e]
  unsigned short* W2T = sm + 54784;   // [64][SX]   W2^T [e][j]
  __shared__ float cmA[2][64], c1A[2][64], ppS[2][2];
  __shared__ float kmomS[64], xmomS[128], w1momS[128], w2momS[64];

  // ---- init state ----
  {
    const int j = tid >> 2, q0 = (tid & 3) * 16;
    const float* w1p = W1in + (size_t)h * D_ * DM_;
    #pragma unroll 4
    for (int t=0;t<16;++t)
      W1T[j*SK + q0 + t] = (unsigned short)f2bfu(w1p[(size_t)(q0+t)*DM_ + j]);
    const float* w2p = W2in + (size_t)h * DM_ * D_ + (size_t)j*D_ + q0;
    #pragma unroll 4
    for (int t=0;t<16;++t){
      unsigned short v = (unsigned short)f2bfu(w2p[t]);
      W2n[j*SK + q0 + t] = v;
      W2T[(q0+t)*SX + j] = v;
    }
  }
  if (tid < 64){ kmomS[tid]=0.f; w2momS[tid]=0.f; }
  if (tid < 128){ xmomS[tid]=0.f; w1momS[tid]=0.f; }

  const int c = h*64 + lane;
  float wkc[4], wqc[4], wvc[4];
  #pragma unroll
  for (int kk=0;kk<4;++kk){ wkc[kk]=ckw[c*4+kk]; wqc[kk]=cqw[c*4+kk]; wvc[kk]=cvw[c*4+kk]; }
  const float bkc = ckb[c], bqc = cqb[c], bvc = cvb[c];
  const float knf = knw[lane], qnf = qnw[lane];
  const long hbase = (long)bh * L_ * 64 + lane;   // head-major, col=lane

  float rk[11], rq[11], rv[11];
  float cmr=0.f, c1r=0.f, ppr=0.f;

  auto stage_load = [&](int m){
    if (m >= NCH_) return;
    const int i0 = wave*8;
    const long sb = hbase + (long)(m*64 + i0)*64;
    #pragma unroll
    for (int t=0;t<11;++t){
      const bool ok = (m*64 + i0 + t - 3) >= 0;
      const long a = sb + (long)(t-3)*64;
      rk[t] = ok ? bf2f(kg[a]) : 0.f;
      rq[t] = ok ? bf2f(qg[a]) : 0.f;
      rv[t] = ok ? bf2f(vg[a]) : 0.f;
    }
    if (wave == 0){
      cmr = cmg[((size_t)bh*NCH_ + m)*64 + lane];
      c1r = c1g[((size_t)bh*NCH_ + m)*64 + lane];
    }
    if (tid < 2) ppr = ppg[((size_t)bh*NCH_ + m)*2 + tid];
  };

  auto stage_compute = [&](int m, int s){
    if (m >= NCH_) return;
    const int i0 = wave*8;
    unsigned short* kc = sm + s*4608;
    unsigned short* qc = sm + 9216 + s*4608;
    unsigned short* gm = sm + 18432 + s*4608;
    #pragma unroll
    for (int i=0;i<8;++i){
      float ak = bkc + wkc[0]*rk[i] + wkc[1]*rk[i+1] + wkc[2]*rk[i+2] + wkc[3]*rk[i+3];
      float aq = bqc + wqc[0]*rq[i] + wqc[1]*rq[i+1] + wqc[2]*rq[i+2] + wqc[3]*rq[i+3];
      float av = bvc + wvc[0]*rv[i] + wvc[1]*rv[i+1] + wvc[2]*rv[i+2] + wvc[3]*rv[i+3];
      const float yk = ak*sigf(ak), yq = aq*sigf(aq), yv = av*sigf(av);
      const float ssk = wsum64(yk*yk);
      const float ssq = wsum64(yq*yq);
      const float vk = knf * yk * rsqrtf(ssk*(1.0f/64.0f) + EPS_);
      const float vq = qnf * yq * rsqrtf(ssq*(1.0f/64.0f) + EPS_);
      const int o = (i0+i)*SK + lane;
      kc[o] = (unsigned short)f2bfu(vk);
      qc[o] = (unsigned short)f2bfu(vq);
      gm[o] = (unsigned short)f2bfu(yv);
    }
    if (wave == 0){ cmA[s][lane] = cmr; c1A[s][lane] = c1r; }
    if (tid < 2) ppS[s][tid] = ppr;
  };

  stage_load(0);
  stage_compute(0, 0);
  __syncthreads();

  for (int n = 0; n < NCH_; ++n){
    const int cur = n & 1, nxt = cur ^ 1;
    const unsigned short* kcs = sm + cur*4608;
    const unsigned short* qcs = sm + 9216 + cur*4608;
    unsigned short* gms = sm + 18432 + cur*4608;

    stage_load(n+1);   // global loads issue here; latency hides under P2

    // ---- P2: Z1 = kc @ W1 ; X1 = silu(Z1) -> xbs ----
    facc_t zk[4];
    {
      const bfrag_t a0 = *(const bfrag_t*)&kcs[(rw+lq)*SK + quad*8];
      const bfrag_t a1 = *(const bfrag_t*)&kcs[(rw+lq)*SK + 32 + quad*8];
      #pragma unroll
      for (int nt=0;nt<4;++nt){
        const int j = cw*64 + nt*16 + lq;
        const bfrag_t b0 = *(const bfrag_t*)&W1T[j*SK + quad*8];
        const bfrag_t b1 = *(const bfrag_t*)&W1T[j*SK + 32 + quad*8];
        facc_t z = {0.f,0.f,0.f,0.f};
        z = MFMA16(a0,b0,z); z = MFMA16(a1,b1,z);
        zk[nt] = z;
        const int r0 = rw + quad*4;
        #pragma unroll
        for (int r=0;r<4;++r)
          xbs[(r0+r)*SX + j] = (unsigned short)f2bfu(z[r]*sigf(z[r]));
      }
    }
    __syncthreads();   // b1

    // ---- P4: g_m = X1 @ W2 - v ; P3: kmom/xmom ; stage compute(n+1) ----
    {
      bfrag_t xa[4];
      #pragma unroll
      for (int kt=0;kt<4;++kt) xa[kt] = *(const bfrag_t*)&xbs[(rw+lq)*SX + kt*32 + quad*8];
      #pragma unroll
      for (int nt=0;nt<2;++nt){
        const int e = cw*32 + nt*16 + lq;
        facc_t z = {0.f,0.f,0.f,0.f};
        #pragma unroll
        for (int kt=0;kt<4;++kt){
          const bfrag_t bb = *(const bfrag_t*)&W2T[e*SX + kt*32 + quad*8];
          z = MFMA16(xa[kt], bb, z);
        }
        const int r0 = rw + quad*4;
        #pragma unroll
        for (int r=0;r<4;++r){
          const float g = z[r] - bf2f(gms[(r0+r)*SK + e]);
          gms[(r0+r)*SK + e] = (unsigned short)f2bfu(g);
        }
      }
    }
    if (tid < 64){
      float a0=0.f,a1=0.f,a2=0.f,a3=0.f;
      #pragma unroll 4
      for (int i=0;i<64;i+=4){
        a0 += cmA[cur][i+0]*bf2f(kcs[(i+0)*SK + tid]);
        a1 += cmA[cur][i+1]*bf2f(kcs[(i+1)*SK + tid]);
        a2 += cmA[cur][i+2]*bf2f(kcs[(i+2)*SK + tid]);
        a3 += cmA[cur][i+3]*bf2f(kcs[(i+3)*SK + tid]);
      }
      kmomS[tid] = ppS[cur][0]*kmomS[tid] + ((a0+a1)+(a2+a3));
    } else if (tid < 192){
      const int j = tid - 64;
      float a0=0.f,a1=0.f,a2=0.f,a3=0.f;
      #pragma unroll 4
      for (int i=0;i<64;i+=4){
        a0 += cmA[cur][i+0]*bf2f(xbs[(i+0)*SX + j]);
        a1 += cmA[cur][i+1]*bf2f(xbs[(i+1)*SX + j]);
        a2 += cmA[cur][i+2]*bf2f(xbs[(i+2)*SX + j]);
        a3 += cmA[cur][i+3]*bf2f(xbs[(i+3)*SX + j]);
      }
      xmomS[j] = ppS[cur][0]*xmomS[j] + ((a0+a1)+(a2+a3));
    }
    stage_compute(n+1, nxt);
    __syncthreads();   // b2

    // ---- P5: gZ1 = (g_m @ W2rows) * silu_bwd(Z1) -> xbs ----
    {
      const bfrag_t a0 = *(const bfrag_t*)&gms[(rw+lq)*SK + quad*8];
      const bfrag_t a1 = *(const bfrag_t*)&gms[(rw+lq)*SK + 32 + quad*8];
      #pragma unroll
      for (int nt=0;nt<4;++nt){
        const int j = cw*64 + nt*16 + lq;
        const bfrag_t b0 = *(const bfrag_t*)&W2n[j*SK + quad*8];
        const bfrag_t b1 = *(const bfrag_t*)&W2n[j*SK + 32 + quad*8];
        facc_t gz = {0.f,0.f,0.f,0.f};
        gz = MFMA16(a0,b0,gz); gz = MFMA16(a1,b1,gz);
        const int r0 = rw + quad*4;
        #pragma unroll
        for (int r=0;r<4;++r){
          const float zz = zk[nt][r];
          const float sg = sigf(zz);
          xbs[(r0+r)*SX + j] = (unsigned short)f2bfu(gz[r] * (sg * (1.0f + zz*(1.0f - sg))));
        }
      }
    }
    __syncthreads();   // b3

    // ---- P6: w1mom / w2mom ----
    if (tid < 128){
      float a0=0.f,a1=0.f,a2=0.f,a3=0.f;
      #pragma unroll 4
      for (int i=0;i<64;i+=4){
        a0 += c1A[cur][i+0]*bf2f(xbs[(i+0)*SX + tid]);
        a1 += c1A[cur][i+1]*bf2f(xbs[(i+1)*SX + tid]);
        a2 += c1A[cur][i+2]*bf2f(xbs[(i+2)*SX + tid]);
        a3 += c1A[cur][i+3]*bf2f(xbs[(i+3)*SX + tid]);
      }
      w1momS[tid] = ppS[cur][1]*w1momS[tid] + ((a0+a1)+(a2+a3));
    } else if (tid < 192){
      const int e = tid - 128;
      float a0=0.f,a1=0.f,a2=0.f,a3=0.f;
      #pragma unroll 4
      for (int i=0;i<64;i+=4){
        a0 += c1A[cur][i+0]*bf2f(gms[(i+0)*SK + e]);
        a1 += c1A[cur][i+1]*bf2f(gms[(i+1)*SK + e]);
        a2 += c1A[cur][i+2]*bf2f(gms[(i+2)*SK + e]);
        a3 += c1A[cur][i+3]*bf2f(gms[(i+3)*SK + e]);
      }
      w2momS[e] = ppS[cur][1]*w2momS[e] + ((a0+a1)+(a2+a3));
    }
    __syncthreads();   // b4

    // ---- P7: rank-1 state updates ----
    {
      const float Pmd = ppS[cur][0];
      const int j = tid >> 2, q0 = (tid & 3)*16;
      const float wm = w1momS[j], xm = xmomS[j];
      #pragma unroll
      for (int half=0; half<16; half+=8){
        const int off = j*SK + q0 + half;
        bfrag_t wv = *(const bfrag_t*)&W1T[off];
        alignas(16) unsigned short o[8];
        #pragma unroll
        for (int s2=0;s2<8;++s2)
          o[s2] = (unsigned short)f2bfu(Pmd*bf2f((unsigned short)wv[s2]) + wm*kmomS[q0+half+s2]);
        *(bfrag_t*)&W1T[off] = *(const bfrag_t*)o;
      }
      #pragma unroll
      for (int half=0; half<16; half+=8){
        const int off = j*SK + q0 + half;
        bfrag_t wv = *(const bfrag_t*)&W2n[off];
        alignas(16) unsigned short o[8];
        #pragma unroll
        for (int s2=0;s2<8;++s2)
          o[s2] = (unsigned short)f2bfu(Pmd*bf2f((unsigned short)wv[s2]) + xm*w2momS[q0+half+s2]);
        *(bfrag_t*)&W2n[off] = *(const bfrag_t*)o;
      }
      const int e2 = tid >> 3, js = (tid & 7)*16;
      const float w2m = w2momS[e2];
      #pragma unroll
      for (int half=0; half<16; half+=8){
        const int off = e2*SX + js + half;
        bfrag_t wv = *(const bfrag_t*)&W2T[off];
        alignas(16) unsigned short o[8];
        #pragma unroll
        for (int s2=0;s2<8;++s2)
          o[s2] = (unsigned short)f2bfu(Pmd*bf2f((unsigned short)wv[s2]) + xmomS[js+half+s2]*w2m);
        *(bfrag_t*)&W2T[off] = *(const bfrag_t*)o;
      }
    }
    __syncthreads();   // b5

    // ---- P8: hq = silu(qc @ W1new) -> xbs ----
    {
      const bfrag_t a0 = *(const bfrag_t*)&qcs[(rw+lq)*SK + quad*8];
      const bfrag_t a1 = *(const bfrag_t*)&qcs[(rw+lq)*SK + 32 + quad*8];
      #pragma unroll
      for (int nt=0;nt<4;++nt){
        const int j = cw*64 + nt*16 + lq;
        const bfrag_t b0 = *(const bfrag_t*)&W1T[j*SK + quad*8];
        const bfrag_t b1 = *(const bfrag_t*)&W1T[j*SK + 32 + quad*8];
        facc_t z = {0.f,0.f,0.f,0.f};
        z = MFMA16(a0,b0,z); z = MFMA16(a1,b1,z);
        const int r0 = rw + quad*4;
        #pragma unroll
        for (int r=0;r<4;++r)
          xbs[(r0+r)*SX + j] = (unsigned short)f2bfu(z[r]*sigf(z[r]));
      }
    }
    __syncthreads();   // b6

    // ---- P9: y = hq @ W2new -> out (B,H,D,L flat) ----
    {
      bfrag_t xa[4];
      #pragma unroll
      for (int kt=0;kt<4;++kt) xa[kt] = *(const bfrag_t*)&xbs[(rw+lq)*SX + kt*32 + quad*8];
      #pragma unroll
      for (int nt=0;nt<2;++nt){
        const int e = cw*32 + nt*16 + lq;
        facc_t y = {0.f,0.f,0.f,0.f};
        #pragma unroll
        for (int kt=0;kt<4;++kt){
          const bfrag_t bb = *(const bfrag_t*)&W2T[e*SX + kt*32 + quad*8];
          y = MFMA16(xa[kt], bb, y);
        }
        float4 ov; ov.x = y[0]; ov.y = y[1]; ov.z = y[2]; ov.w = y[3];
        *(float4*)&out[(size_t)bh*D_*L_ + (size_t)e*L_ + n*64 + rw + quad*4] = ov;
      }
    }
    __syncthreads();   // b7
  }
}

extern "C" void kernel_launch(void* const* d_in, const int* in_sizes, int n_in,
                              void* d_out, int out_size, void* d_ws, size_t ws_size,
                              hipStream_t stream)
{
  const float* x   = (const float*)d_in[0];
  const float* Wq  = (const float*)d_in[1];
  const float* Wk  = (const float*)d_in[2];
  const float* Wv  = (const float*)d_in[3];
  const float* cqw = (const float*)d_in[4];
  const float* cqb = (const float*)d_in[5];
  const float* ckw = (const float*)d_in[6];
  const float* ckb = (const float*)d_in[7];
  const float* cvw = (const float*)d_in[8];
  const float* cvb = (const float*)d_in[9];
  const float* qnw = (const float*)d_in[10];
  const float* knw = (const float*)d_in[11];
  const float* mdw = (const float*)d_in[12];
  const float* mdb = (const float*)d_in[13];
  const float* sw  = (const float*)d_in[14];
  const float* sb  = (const float*)d_in[15];
  const float* lw  = (const float*)d_in[16];
  const float* lb  = (const float*)d_in[17];
  const float* W1  = (const float*)d_in[18];
  const float* W2  = (const float*)d_in[19];
  float* out = (float*)d_out;

  const size_t SZ  = (size_t)B_ * L_ * HID_;   // 16,777,216
  const size_t WSZ = (size_t)HID_ * HID_;      //  1,048,576
  unsigned short* xb  = (unsigned short*)d_ws;
  unsigned short* wqb = xb  + SZ;      // wq/wk/wv contiguous = Wcat[3072][1024]
  unsigned short* wkb = wqb + WSZ;
  unsigned short* wvb = wkb + WSZ;
  unsigned short* qb  = wvb + WSZ;     // q/k/v contiguous, head-major each
  unsigned short* kb  = qb  + SZ;
  unsigned short* vb  = kb  + SZ;
  float* cmb = (float*)(vb + SZ);
  float* c1b = cmb + (size_t)B_*H_*NCH_*64;
  float* ppb = c1b + (size_t)B_*H_*NCH_*64;

  cast_kernel<<<16384 + 3*1024, 256, 0, stream>>>(x, Wq, Wk, Wv, xb, wqb, wkb, wvb);
  dim3 gg(3*HID_/128, (B_*L_)/128);
  gemm_bf16_nt<<<gg, 256, 0, stream>>>(xb, wqb, qb, B_*L_, 3*HID_, HID_);
  gates_kernel<<<(B_*L_)/64, 256, 0, stream>>>(x, mdw, mdb, sw, sb, lw, lb, cmb, c1b, ppb);
  scan_kernel<<<B_*H_, 512, 0, stream>>>(qb, kb, vb, cmb, c1b, ppb,
                                         cqw, cqb, ckw, ckb, cvw, cvb,
                                         qnw, knw, W1, W2, out);
}